// Round 2
// baseline (1754.005 us; speedup 1.0000x reference)
//
#include <hip/hip_runtime.h>

// ---------------- problem constants ----------------
#define S_LEN   2048
#define NH      16
#define DKH     128
#define DIM     2048
#define KD      2048
#define VD      2048
#define MB      1048576ull

typedef short  short8  __attribute__((ext_vector_type(8)));
typedef short  short4v __attribute__((ext_vector_type(4)));
typedef float  floatx4 __attribute__((ext_vector_type(4)));

// fp32 -> bf16, round-to-nearest-even
__device__ inline short f2bf(float x) {
    unsigned u = __float_as_uint(x);
    unsigned r = (u + 0x7fffu + ((u >> 16) & 1u)) >> 16;
    return (short)r;
}
__device__ inline float bf2f(short s) {
    return __uint_as_float(((unsigned)(unsigned short)s) << 16);
}
__device__ inline float silu_f(float x) { return x / (1.f + __expf(-x)); }

// async global->LDS, 16B per lane; LDS dest is wave-uniform base (+lane*16 implicit)
__device__ inline void load_lds16(const void* g, void* l) {
    __builtin_amdgcn_global_load_lds(
        (const __attribute__((address_space(1))) unsigned int*)g,
        (__attribute__((address_space(3))) unsigned int*)l, 16, 0, 0);
}

// ---------------- fp32 -> bf16 conversion ----------------
__global__ __launch_bounds__(256) void cvt_bf16_kernel(const float* __restrict__ in,
                                                       short* __restrict__ out, int n8) {
    int i = blockIdx.x * 256 + threadIdx.x;
    if (i >= n8) return;
    float4 a = ((const float4*)in)[2 * i];
    float4 b = ((const float4*)in)[2 * i + 1];
    short8 o;
    o[0] = f2bf(a.x); o[1] = f2bf(a.y); o[2] = f2bf(a.z); o[3] = f2bf(a.w);
    o[4] = f2bf(b.x); o[5] = f2bf(b.y); o[6] = f2bf(b.z); o[7] = f2bf(b.w);
    ((short8*)out)[i] = o;
}

// ---------------- bf16 MFMA GEMM:  C[m,n] = sum_k A[m,k]*B[n,k] ----------------
// 128x128 tile, BK=32, 256 threads (4 waves 2x2), 16x16x32 MFMA, 4x4 frags/wave.
__device__ inline void store_c(float* C, size_t idx, float v) { C[idx] = v; }
__device__ inline void store_c(short* C, size_t idx, float v) { C[idx] = f2bf(v); }

template <typename OutT>
__device__ inline void gemm_tile(const short* __restrict__ A, const short* __restrict__ Bw,
                                 OutT* __restrict__ C, int mtile, int ntile) {
    __shared__ short lA[128 * 32];
    __shared__ short lB[128 * 32];
    const int K = 2048, N = 2048;
    int t    = threadIdx.x;
    int wave = t >> 6;
    int lane = t & 63;
    int m0 = mtile * 128, n0 = ntile * 128;
    int wm = (wave & 1) * 64;
    int wn = (wave >> 1) * 64;

    floatx4 acc[4][4];
#pragma unroll
    for (int i = 0; i < 4; ++i)
#pragma unroll
        for (int j = 0; j < 4; ++j) acc[i][j] = (floatx4){0.f, 0.f, 0.f, 0.f};

    int fr = lane & 15;
    int fk = (lane >> 4) * 8;

    for (int k0 = 0; k0 < K; k0 += 32) {
#pragma unroll
        for (int p = 0; p < 2; ++p) {
            int c   = p * 256 + t;
            int row = c >> 2, kp = c & 3;
            const short* ga = A  + (size_t)(m0 + row) * K + k0 + kp * 8;
            const short* gb = Bw + (size_t)(n0 + row) * K + k0 + kp * 8;
            short* la = lA + (size_t)(p * 256 + wave * 64) * 8;  // wave-uniform base
            short* lb = lB + (size_t)(p * 256 + wave * 64) * 8;
            load_lds16(ga, la);
            load_lds16(gb, lb);
        }
        __syncthreads();
        short8 af[4], bfr[4];
#pragma unroll
        for (int i = 0; i < 4; ++i) af[i]  = *(const short8*)(lA + (wm + i * 16 + fr) * 32 + fk);
#pragma unroll
        for (int j = 0; j < 4; ++j) bfr[j] = *(const short8*)(lB + (wn + j * 16 + fr) * 32 + fk);
#pragma unroll
        for (int i = 0; i < 4; ++i)
#pragma unroll
            for (int j = 0; j < 4; ++j)
                acc[i][j] = __builtin_amdgcn_mfma_f32_16x16x32_bf16(af[i], bfr[j], acc[i][j], 0, 0, 0);
        __syncthreads();
    }
    // C/D layout: col = lane&15, row = (lane>>4)*4 + reg
    int cr = (lane >> 4) * 4;
    int cc = lane & 15;
#pragma unroll
    for (int i = 0; i < 4; ++i)
#pragma unroll
        for (int j = 0; j < 4; ++j)
#pragma unroll
            for (int r = 0; r < 4; ++r)
                store_c(C, (size_t)(m0 + wm + i * 16 + cr + r) * N + (n0 + wn + j * 16 + cc),
                        acc[i][j][r]);
}

__global__ __launch_bounds__(256) void gemm_qkvg(const short* __restrict__ A,
    const short* __restrict__ B0, const short* __restrict__ B1,
    const short* __restrict__ B2, const short* __restrict__ B3,
    short* __restrict__ C0, short* __restrict__ C1,
    short* __restrict__ C2, short* __restrict__ C3) {
    const short* Bw; short* C;
    switch (blockIdx.z) {
        case 0:  Bw = B0; C = C0; break;
        case 1:  Bw = B1; C = C1; break;
        case 2:  Bw = B2; C = C2; break;
        default: Bw = B3; C = C3; break;
    }
    gemm_tile<short>(A, Bw, C, blockIdx.x, blockIdx.y);
}

__global__ __launch_bounds__(256) void gemm_out(const short* __restrict__ A,
    const short* __restrict__ Bw, float* __restrict__ C) {
    gemm_tile<float>(A, Bw, C, blockIdx.x, blockIdx.y);
}

// ---------------- a/b projection + decay/beta transform ----------------
__global__ __launch_bounds__(256) void ab_kernel(const float* __restrict__ x,
    const float* __restrict__ Wa, const float* __restrict__ Wb,
    const float* __restrict__ Alog, const float* __restrict__ dtb,
    float* __restrict__ gdec, float* __restrict__ beta) {
    __shared__ float xs[2048];
    __shared__ float red[32][9];
    int m = blockIdx.x, t = threadIdx.x;
    const float* xr = x + (size_t)m * DIM;
    for (int i = t; i < 512; i += 256) ((float4*)xs)[i] = ((const float4*)xr)[i];
    __syncthreads();
    int col = t >> 3, part = t & 7;
    const float* wr = (col < 16) ? (Wa + (size_t)col * DIM) : (Wb + (size_t)(col - 16) * DIM);
    float s = 0.f;
    int kb = part * 256;
#pragma unroll 4
    for (int k = 0; k < 256; k += 4) {
        float4 xv = *(const float4*)(xs + kb + k);
        float4 wv = *(const float4*)(wr + kb + k);
        s += xv.x * wv.x + xv.y * wv.y + xv.z * wv.z + xv.w * wv.w;
    }
    red[col][part] = s;
    __syncthreads();
    if (t < 32) {
        float a = 0.f;
#pragma unroll
        for (int p = 0; p < 8; ++p) a += red[t][p];
        if (t < 16) {
            float sp = a + dtb[t];
            float softp = (sp > 20.f) ? sp : log1pf(expf(sp));
            gdec[(size_t)m * NH + t] = expf(-expf(Alog[t]) * softp);
        } else {
            int h = t - 16;
            beta[(size_t)m * NH + h] = 1.f / (1.f + expf(-a));
        }
    }
}

// ---------------- causal conv (K=4) + SiLU + l2norm(q,k)  (bf16 in/out) ----------------
// one wave per (row m, head h); 2 channels per lane
__global__ __launch_bounds__(256) void conv_kernel(
    const short* __restrict__ qr, const short* __restrict__ kr, const short* __restrict__ vr,
    const float* __restrict__ cwq, const float* __restrict__ cbq,
    const float* __restrict__ cwk, const float* __restrict__ cbk,
    const float* __restrict__ cwv, const float* __restrict__ cbv,
    short* __restrict__ qn, short* __restrict__ kn, short* __restrict__ vc) {
    int gw   = blockIdx.x * 4 + (threadIdx.x >> 6);
    int lane = threadIdx.x & 63;
    int h  = gw & (NH - 1);
    int m  = gw >> 4;
    int tt = m & (S_LEN - 1);
    int c  = h * DKH + lane * 2;
    size_t rowbase = (size_t)m * KD + c;

    float4 wq0 = ((const float4*)cwq)[c], wq1 = ((const float4*)cwq)[c + 1];
    float4 wk0 = ((const float4*)cwk)[c], wk1 = ((const float4*)cwk)[c + 1];
    float4 wv0 = ((const float4*)cwv)[c], wv1 = ((const float4*)cwv)[c + 1];
    float q0 = cbq[c], q1 = cbq[c + 1];
    float k0 = cbk[c], k1 = cbk[c + 1];
    float v0 = cbv[c], v1 = cbv[c + 1];
    const float* wq0a = (const float*)&wq0; const float* wq1a = (const float*)&wq1;
    const float* wk0a = (const float*)&wk0; const float* wk1a = (const float*)&wk1;
    const float* wv0a = (const float*)&wv0; const float* wv1a = (const float*)&wv1;
#pragma unroll
    for (int j = 0; j < 4; ++j) {
        int ts = tt - 3 + j;
        if (ts >= 0) {
            long long rb = (long long)rowbase + (long long)(j - 3) * KD;
            unsigned uq = *(const unsigned*)(qr + rb);
            unsigned uk = *(const unsigned*)(kr + rb);
            unsigned uv = *(const unsigned*)(vr + rb);
            q0 += bf2f((short)(uq & 0xffff)) * wq0a[j]; q1 += bf2f((short)(uq >> 16)) * wq1a[j];
            k0 += bf2f((short)(uk & 0xffff)) * wk0a[j]; k1 += bf2f((short)(uk >> 16)) * wk1a[j];
            v0 += bf2f((short)(uv & 0xffff)) * wv0a[j]; v1 += bf2f((short)(uv >> 16)) * wv1a[j];
        }
    }
    q0 = silu_f(q0); q1 = silu_f(q1);
    k0 = silu_f(k0); k1 = silu_f(k1);
    v0 = silu_f(v0); v1 = silu_f(v1);

    float sq = q0 * q0 + q1 * q1;
    float sk = k0 * k0 + k1 * k1;
#pragma unroll
    for (int off = 1; off < 64; off <<= 1) {
        sq += __shfl_xor(sq, off);
        sk += __shfl_xor(sk, off);
    }
    float iq = 1.f / fmaxf(sqrtf(sq), 1e-12f);
    float ik = 1.f / fmaxf(sqrtf(sk), 1e-12f);
    unsigned oq = (unsigned)(unsigned short)f2bf(q0 * iq) | ((unsigned)(unsigned short)f2bf(q1 * iq) << 16);
    unsigned ok = (unsigned)(unsigned short)f2bf(k0 * ik) | ((unsigned)(unsigned short)f2bf(k1 * ik) << 16);
    unsigned ov = (unsigned)(unsigned short)f2bf(v0)      | ((unsigned)(unsigned short)f2bf(v1)      << 16);
    *(unsigned*)(qn + rowbase) = oq;
    *(unsigned*)(kn + rowbase) = ok;
    *(unsigned*)(vc + rowbase) = ov;
}

// ---------------- gated delta-rule scan (bf16 in/out, fp32 state) ----------------
// wave = (b, h, column-pair). 32 lanes per column, 4 state elems per lane (k-dim).
__global__ __launch_bounds__(256) void scan_kernel(
    const short* __restrict__ qn, const short* __restrict__ kn, const short* __restrict__ vc,
    const float* __restrict__ gdec, const float* __restrict__ beta, short* __restrict__ o) {
    int gw   = (blockIdx.x * 256 + threadIdx.x) >> 6;  // 0..2047
    int lane = threadIdx.x & 63;
    int bh      = gw >> 6;   // 0..31
    int colpair = gw & 63;   // 0..63
    int b = bh >> 4, h = bh & 15;
    int col  = colpair * 2 + (lane & 1);
    int krow = (lane >> 1) * 4;

    float s0 = 0.f, s1 = 0.f, s2 = 0.f, s3 = 0.f;
    size_t baseBH = ((size_t)b * S_LEN * NH + h) * 128;
    const short* qp = qn + baseBH + krow;
    const short* kp = kn + baseBH + krow;
    const short* vp = vc + baseBH + col;
    const float* gp = gdec + (size_t)b * S_LEN * NH + h;
    const float* bp = beta + (size_t)b * S_LEN * NH + h;
    short* op = o + baseBH + col;

    short4v kv = *(const short4v*)kp;
    short4v qv = *(const short4v*)qp;
    short  vv = *vp;
    float  gt = *gp, bt = *bp;

    for (int t = 0; t < S_LEN; ++t) {
        short4v kc = kv, qc = qv;
        short  vcur = vv;
        float  gc = gt, bc = bt;
        if (t < S_LEN - 1) {  // prefetch next step
            kp += 2048; qp += 2048; vp += 2048; gp += NH; bp += NH;
            kv = *(const short4v*)kp;
            qv = *(const short4v*)qp;
            vv = *vp; gt = *gp; bt = *bp;
        }
        float k0 = bf2f(kc[0]), k1 = bf2f(kc[1]), k2 = bf2f(kc[2]), k3 = bf2f(kc[3]);
        float r = s0 * k0 + s1 * k1 + s2 * k2 + s3 * k3;
        r += __shfl_xor(r, 2);  r += __shfl_xor(r, 4);  r += __shfl_xor(r, 8);
        r += __shfl_xor(r, 16); r += __shfl_xor(r, 32);
        float u = bc * (bf2f(vcur) - gc * r);
        s0 = gc * s0 + k0 * u; s1 = gc * s1 + k1 * u;
        s2 = gc * s2 + k2 * u; s3 = gc * s3 + k3 * u;
        float oo = s0 * bf2f(qc[0]) + s1 * bf2f(qc[1]) + s2 * bf2f(qc[2]) + s3 * bf2f(qc[3]);
        oo += __shfl_xor(oo, 2);  oo += __shfl_xor(oo, 4);  oo += __shfl_xor(oo, 8);
        oo += __shfl_xor(oo, 16); oo += __shfl_xor(oo, 32);
        if (lane < 2) *op = f2bf(oo);
        op += 2048;
    }
}

// ---------------- RMSNorm + SiLU gate (bf16 in/out) ----------------
__global__ __launch_bounds__(256) void rms_gate_kernel(
    const short* __restrict__ o, const short* __restrict__ graw,
    const float* __restrict__ nw, short* __restrict__ og) {
    __shared__ float red[4];
    int m = blockIdx.x, t = threadIdx.x;
    short8 a = ((const short8*)(o + (size_t)m * VD))[t];
    float av[8];
#pragma unroll
    for (int i = 0; i < 8; ++i) av[i] = bf2f(a[i]);
    float ss = 0.f;
#pragma unroll
    for (int i = 0; i < 8; ++i) ss += av[i] * av[i];
#pragma unroll
    for (int off = 1; off < 64; off <<= 1) ss += __shfl_xor(ss, off);
    if ((t & 63) == 0) red[t >> 6] = ss;
    __syncthreads();
    float tot = red[0] + red[1] + red[2] + red[3];
    float sc = rsqrtf(tot * (1.f / VD) + 1e-6f);
    short8 gv = ((const short8*)(graw + (size_t)m * VD))[t];
    float4 n0 = ((const float4*)nw)[2 * t];
    float4 n1 = ((const float4*)nw)[2 * t + 1];
    const float* na = (const float*)&n0;
    const float* nb = (const float*)&n1;
    short8 ov;
#pragma unroll
    for (int i = 0; i < 4; ++i) ov[i]     = f2bf(av[i]     * sc * na[i] * silu_f(bf2f(gv[i])));
#pragma unroll
    for (int i = 0; i < 4; ++i) ov[i + 4] = f2bf(av[i + 4] * sc * nb[i] * silu_f(bf2f(gv[i + 4])));
    ((short8*)(og + (size_t)m * VD))[t] = ov;
}

// ---------------- host launcher ----------------
extern "C" void kernel_launch(void* const* d_in, const int* in_sizes, int n_in,
                              void* d_out, int out_size, void* d_ws, size_t ws_size,
                              hipStream_t stream) {
    const float* x    = (const float*)d_in[0];
    const float* Wq   = (const float*)d_in[1];
    const float* Wk   = (const float*)d_in[2];
    const float* Wv   = (const float*)d_in[3];
    const float* Wa   = (const float*)d_in[4];
    const float* Wb   = (const float*)d_in[5];
    const float* Wg   = (const float*)d_in[6];
    const float* Wo   = (const float*)d_in[7];
    const float* cwq  = (const float*)d_in[8];
    const float* cbq  = (const float*)d_in[9];
    const float* cwk  = (const float*)d_in[10];
    const float* cbk  = (const float*)d_in[11];
    const float* cwv  = (const float*)d_in[12];
    const float* cbv  = (const float*)d_in[13];
    const float* Alog = (const float*)d_in[14];
    const float* dtb  = (const float*)d_in[15];
    const float* nw   = (const float*)d_in[16];

    // workspace layout (peak 120.5 MiB):
    //   [0,8)    Wob            (live to end)
    //   [8,24)   xb   -> qnb    (xb dead after gemm1)
    //   [24,40)  Wqb/Wkb -> knb
    //   [40,56)  Wvb/Wgb -> vnb
    //   [56,72)  qrb  -> ob     (qrb dead after conv)
    //   [72,88)  krb  -> ogb
    //   [88,104) vrb
    //   [104,120) grb           (live to rms_gate)
    //   [120,120.5) gdec, beta
    char* ws = (char*)d_ws;
    short* Wob = (short*)(ws);
    short* xb  = (short*)(ws + 8 * MB);
    short* Wqb = (short*)(ws + 24 * MB);
    short* Wkb = (short*)(ws + 32 * MB);
    short* Wvb = (short*)(ws + 40 * MB);
    short* Wgb = (short*)(ws + 48 * MB);
    short* qrb = (short*)(ws + 56 * MB);
    short* krb = (short*)(ws + 72 * MB);
    short* vrb = (short*)(ws + 88 * MB);
    short* grb = (short*)(ws + 104 * MB);
    short* qnb = (short*)(ws + 8 * MB);
    short* knb = (short*)(ws + 24 * MB);
    short* vnb = (short*)(ws + 40 * MB);
    float* gdec = (float*)(ws + 120 * MB);
    float* beta = (float*)(ws + 120 * MB + 262144);
    short* ob  = qrb;   // reuse
    short* ogb = krb;   // reuse

    // 1. fp32 -> bf16 conversions
    cvt_bf16_kernel<<<4096, 256, 0, stream>>>(x,  xb,  1048576);
    cvt_bf16_kernel<<<2048, 256, 0, stream>>>(Wq, Wqb, 524288);
    cvt_bf16_kernel<<<2048, 256, 0, stream>>>(Wk, Wkb, 524288);
    cvt_bf16_kernel<<<2048, 256, 0, stream>>>(Wv, Wvb, 524288);
    cvt_bf16_kernel<<<2048, 256, 0, stream>>>(Wg, Wgb, 524288);
    cvt_bf16_kernel<<<2048, 256, 0, stream>>>(Wo, Wob, 524288);

    // 2. a/b projection + decay/beta (fp32, small)
    ab_kernel<<<4096, 256, 0, stream>>>(x, Wa, Wb, Alog, dtb, gdec, beta);

    // 3. fused q/k/v/gate projections (bf16 MFMA), bf16 outputs
    gemm_qkvg<<<dim3(32, 16, 4), 256, 0, stream>>>(xb, Wqb, Wkb, Wvb, Wgb,
                                                   qrb, krb, vrb, grb);

    // 4. causal conv + SiLU + l2norm
    conv_kernel<<<16384, 256, 0, stream>>>(qrb, krb, vrb,
                                           cwq, cbq, cwk, cbk, cwv, cbv, qnb, knb, vnb);

    // 5. gated delta-rule scan
    scan_kernel<<<512, 256, 0, stream>>>(qnb, knb, vnb, gdec, beta, ob);

    // 6. RMSNorm + SiLU gate
    rms_gate_kernel<<<4096, 256, 0, stream>>>(ob, grb, nw, ogb);

    // 7. output projection (fp32 out)
    gemm_out<<<dim3(32, 16, 1), 256, 0, stream>>>(ogb, Wob, (float*)d_out);
}

// Round 3
// 1468.943 us; speedup vs baseline: 1.1941x; 1.1941x over previous
//
#include <hip/hip_runtime.h>

// ---------------- problem constants ----------------
#define S_LEN   2048
#define NH      16
#define DKH     128
#define DIM     2048
#define KD      2048
#define VD      2048
#define MB      1048576ull
#define PF      8       // scan prefetch depth (power of 2, divides S_LEN)

typedef short  short8  __attribute__((ext_vector_type(8)));
typedef short  short4v __attribute__((ext_vector_type(4)));
typedef float  floatx4 __attribute__((ext_vector_type(4)));

// fp32 -> bf16, round-to-nearest-even
__device__ inline short f2bf(float x) {
    unsigned u = __float_as_uint(x);
    unsigned r = (u + 0x7fffu + ((u >> 16) & 1u)) >> 16;
    return (short)r;
}
__device__ inline float bf2f(short s) {
    return __uint_as_float(((unsigned)(unsigned short)s) << 16);
}
__device__ inline float silu_f(float x) { return x / (1.f + __expf(-x)); }

// async global->LDS, 16B per lane; LDS dest is wave-uniform base (+lane*16 implicit)
__device__ inline void load_lds16(const void* g, void* l) {
    __builtin_amdgcn_global_load_lds(
        (const __attribute__((address_space(1))) unsigned int*)g,
        (__attribute__((address_space(3))) unsigned int*)l, 16, 0, 0);
}

// ---------------- fp32 -> bf16 conversion ----------------
__global__ __launch_bounds__(256) void cvt_bf16_kernel(const float* __restrict__ in,
                                                       short* __restrict__ out, int n8) {
    int i = blockIdx.x * 256 + threadIdx.x;
    if (i >= n8) return;
    float4 a = ((const float4*)in)[2 * i];
    float4 b = ((const float4*)in)[2 * i + 1];
    short8 o;
    o[0] = f2bf(a.x); o[1] = f2bf(a.y); o[2] = f2bf(a.z); o[3] = f2bf(a.w);
    o[4] = f2bf(b.x); o[5] = f2bf(b.y); o[6] = f2bf(b.z); o[7] = f2bf(b.w);
    ((short8*)out)[i] = o;
}

// ---------------- bf16 MFMA GEMM:  C[m,n] = sum_k A[m,k]*B[n,k] ----------------
// 128x128 tile, BK=32, 256 threads (4 waves 2x2), 16x16x32 MFMA, 4x4 frags/wave.
__device__ inline void store_c(float* C, size_t idx, float v) { C[idx] = v; }
__device__ inline void store_c(short* C, size_t idx, float v) { C[idx] = f2bf(v); }

template <typename OutT>
__device__ inline void gemm_tile(const short* __restrict__ A, const short* __restrict__ Bw,
                                 OutT* __restrict__ C, int mtile, int ntile) {
    __shared__ short lA[128 * 32];
    __shared__ short lB[128 * 32];
    const int K = 2048, N = 2048;
    int t    = threadIdx.x;
    int wave = t >> 6;
    int lane = t & 63;
    int m0 = mtile * 128, n0 = ntile * 128;
    int wm = (wave & 1) * 64;
    int wn = (wave >> 1) * 64;

    floatx4 acc[4][4];
#pragma unroll
    for (int i = 0; i < 4; ++i)
#pragma unroll
        for (int j = 0; j < 4; ++j) acc[i][j] = (floatx4){0.f, 0.f, 0.f, 0.f};

    int fr = lane & 15;
    int fk = (lane >> 4) * 8;

    for (int k0 = 0; k0 < K; k0 += 32) {
#pragma unroll
        for (int p = 0; p < 2; ++p) {
            int c   = p * 256 + t;
            int row = c >> 2, kp = c & 3;
            const short* ga = A  + (size_t)(m0 + row) * K + k0 + kp * 8;
            const short* gb = Bw + (size_t)(n0 + row) * K + k0 + kp * 8;
            short* la = lA + (size_t)(p * 256 + wave * 64) * 8;  // wave-uniform base
            short* lb = lB + (size_t)(p * 256 + wave * 64) * 8;
            load_lds16(ga, la);
            load_lds16(gb, lb);
        }
        __syncthreads();
        short8 af[4], bfr[4];
#pragma unroll
        for (int i = 0; i < 4; ++i) af[i]  = *(const short8*)(lA + (wm + i * 16 + fr) * 32 + fk);
#pragma unroll
        for (int j = 0; j < 4; ++j) bfr[j] = *(const short8*)(lB + (wn + j * 16 + fr) * 32 + fk);
#pragma unroll
        for (int i = 0; i < 4; ++i)
#pragma unroll
            for (int j = 0; j < 4; ++j)
                acc[i][j] = __builtin_amdgcn_mfma_f32_16x16x32_bf16(af[i], bfr[j], acc[i][j], 0, 0, 0);
        __syncthreads();
    }
    // C/D layout: col = lane&15, row = (lane>>4)*4 + reg
    int cr = (lane >> 4) * 4;
    int cc = lane & 15;
#pragma unroll
    for (int i = 0; i < 4; ++i)
#pragma unroll
        for (int j = 0; j < 4; ++j)
#pragma unroll
            for (int r = 0; r < 4; ++r)
                store_c(C, (size_t)(m0 + wm + i * 16 + cr + r) * N + (n0 + wn + j * 16 + cc),
                        acc[i][j][r]);
}

__global__ __launch_bounds__(256) void gemm_qkvg(const short* __restrict__ A,
    const short* __restrict__ B0, const short* __restrict__ B1,
    const short* __restrict__ B2, const short* __restrict__ B3,
    short* __restrict__ C0, short* __restrict__ C1,
    short* __restrict__ C2, short* __restrict__ C3) {
    const short* Bw; short* C;
    switch (blockIdx.z) {
        case 0:  Bw = B0; C = C0; break;
        case 1:  Bw = B1; C = C1; break;
        case 2:  Bw = B2; C = C2; break;
        default: Bw = B3; C = C3; break;
    }
    gemm_tile<short>(A, Bw, C, blockIdx.x, blockIdx.y);
}

__global__ __launch_bounds__(256) void gemm_out(const short* __restrict__ A,
    const short* __restrict__ Bw, float* __restrict__ C) {
    gemm_tile<float>(A, Bw, C, blockIdx.x, blockIdx.y);
}

// ---------------- a/b projection + decay/beta transform ----------------
__global__ __launch_bounds__(256) void ab_kernel(const float* __restrict__ x,
    const float* __restrict__ Wa, const float* __restrict__ Wb,
    const float* __restrict__ Alog, const float* __restrict__ dtb,
    float* __restrict__ gdec, float* __restrict__ beta) {
    __shared__ float xs[2048];
    __shared__ float red[32][9];
    int m = blockIdx.x, t = threadIdx.x;
    const float* xr = x + (size_t)m * DIM;
    for (int i = t; i < 512; i += 256) ((float4*)xs)[i] = ((const float4*)xr)[i];
    __syncthreads();
    int col = t >> 3, part = t & 7;
    const float* wr = (col < 16) ? (Wa + (size_t)col * DIM) : (Wb + (size_t)(col - 16) * DIM);
    float s = 0.f;
    int kb = part * 256;
#pragma unroll 4
    for (int k = 0; k < 256; k += 4) {
        float4 xv = *(const float4*)(xs + kb + k);
        float4 wv = *(const float4*)(wr + kb + k);
        s += xv.x * wv.x + xv.y * wv.y + xv.z * wv.z + xv.w * wv.w;
    }
    red[col][part] = s;
    __syncthreads();
    if (t < 32) {
        float a = 0.f;
#pragma unroll
        for (int p = 0; p < 8; ++p) a += red[t][p];
        if (t < 16) {
            float sp = a + dtb[t];
            float softp = (sp > 20.f) ? sp : log1pf(expf(sp));
            gdec[(size_t)m * NH + t] = expf(-expf(Alog[t]) * softp);
        } else {
            int h = t - 16;
            beta[(size_t)m * NH + h] = 1.f / (1.f + expf(-a));
        }
    }
}

// ---------------- causal conv (K=4) + SiLU + l2norm(q,k)  (bf16 in/out) ----------------
__global__ __launch_bounds__(256) void conv_kernel(
    const short* __restrict__ qr, const short* __restrict__ kr, const short* __restrict__ vr,
    const float* __restrict__ cwq, const float* __restrict__ cbq,
    const float* __restrict__ cwk, const float* __restrict__ cbk,
    const float* __restrict__ cwv, const float* __restrict__ cbv,
    short* __restrict__ qn, short* __restrict__ kn, short* __restrict__ vc) {
    int gw   = blockIdx.x * 4 + (threadIdx.x >> 6);
    int lane = threadIdx.x & 63;
    int h  = gw & (NH - 1);
    int m  = gw >> 4;
    int tt = m & (S_LEN - 1);
    int c  = h * DKH + lane * 2;
    size_t rowbase = (size_t)m * KD + c;

    float4 wq0 = ((const float4*)cwq)[c], wq1 = ((const float4*)cwq)[c + 1];
    float4 wk0 = ((const float4*)cwk)[c], wk1 = ((const float4*)cwk)[c + 1];
    float4 wv0 = ((const float4*)cwv)[c], wv1 = ((const float4*)cwv)[c + 1];
    float q0 = cbq[c], q1 = cbq[c + 1];
    float k0 = cbk[c], k1 = cbk[c + 1];
    float v0 = cbv[c], v1 = cbv[c + 1];
    const float* wq0a = (const float*)&wq0; const float* wq1a = (const float*)&wq1;
    const float* wk0a = (const float*)&wk0; const float* wk1a = (const float*)&wk1;
    const float* wv0a = (const float*)&wv0; const float* wv1a = (const float*)&wv1;
#pragma unroll
    for (int j = 0; j < 4; ++j) {
        int ts = tt - 3 + j;
        if (ts >= 0) {
            long long rb = (long long)rowbase + (long long)(j - 3) * KD;
            unsigned uq = *(const unsigned*)(qr + rb);
            unsigned uk = *(const unsigned*)(kr + rb);
            unsigned uv = *(const unsigned*)(vr + rb);
            q0 += bf2f((short)(uq & 0xffff)) * wq0a[j]; q1 += bf2f((short)(uq >> 16)) * wq1a[j];
            k0 += bf2f((short)(uk & 0xffff)) * wk0a[j]; k1 += bf2f((short)(uk >> 16)) * wk1a[j];
            v0 += bf2f((short)(uv & 0xffff)) * wv0a[j]; v1 += bf2f((short)(uv >> 16)) * wv1a[j];
        }
    }
    q0 = silu_f(q0); q1 = silu_f(q1);
    k0 = silu_f(k0); k1 = silu_f(k1);
    v0 = silu_f(v0); v1 = silu_f(v1);

    float sq = q0 * q0 + q1 * q1;
    float sk = k0 * k0 + k1 * k1;
#pragma unroll
    for (int off = 1; off < 64; off <<= 1) {
        sq += __shfl_xor(sq, off);
        sk += __shfl_xor(sk, off);
    }
    float iq = 1.f / fmaxf(sqrtf(sq), 1e-12f);
    float ik = 1.f / fmaxf(sqrtf(sk), 1e-12f);
    unsigned oq = (unsigned)(unsigned short)f2bf(q0 * iq) | ((unsigned)(unsigned short)f2bf(q1 * iq) << 16);
    unsigned ok = (unsigned)(unsigned short)f2bf(k0 * ik) | ((unsigned)(unsigned short)f2bf(k1 * ik) << 16);
    unsigned ov = (unsigned)(unsigned short)f2bf(v0)      | ((unsigned)(unsigned short)f2bf(v1)      << 16);
    *(unsigned*)(qn + rowbase) = oq;
    *(unsigned*)(kn + rowbase) = ok;
    *(unsigned*)(vc + rowbase) = ov;
}

// ---------------- gated delta-rule scan (bf16 in/out, fp32 state) ----------------
// wave = (b, h, column-pair). 32 lanes per column, 4 state elems per lane (k-dim).
// Deep register-ring prefetch (PF steps ahead) hides global-load latency;
// remaining cost is the serial shfl-reduction chain per timestep.
__global__ __launch_bounds__(256) void scan_kernel(
    const short* __restrict__ qn, const short* __restrict__ kn, const short* __restrict__ vc,
    const float* __restrict__ gdec, const float* __restrict__ beta, short* __restrict__ o) {
    int gw   = (blockIdx.x * 256 + threadIdx.x) >> 6;  // 0..2047
    int lane = threadIdx.x & 63;
    int bh      = gw >> 6;   // 0..31
    int colpair = gw & 63;   // 0..63
    int b = bh >> 4, h = bh & 15;
    int col  = colpair * 2 + (lane & 1);
    int krow = (lane >> 1) * 4;

    float s0 = 0.f, s1 = 0.f, s2 = 0.f, s3 = 0.f;
    size_t baseBH = ((size_t)b * S_LEN * NH + h) * 128;
    const short* qp = qn + baseBH + krow;
    const short* kp = kn + baseBH + krow;
    const short* vp = vc + baseBH + col;
    const float* gp = gdec + (size_t)b * S_LEN * NH + h;
    const float* bp = beta + (size_t)b * S_LEN * NH + h;
    short* op = o + baseBH + col;

    short4v kbuf[PF], qbuf[PF];
    short   vbuf[PF];
    float   gbuf[PF], bbuf[PF];
#pragma unroll
    for (int j = 0; j < PF; ++j) {
        kbuf[j] = *(const short4v*)kp;
        qbuf[j] = *(const short4v*)qp;
        vbuf[j] = *vp; gbuf[j] = *gp; bbuf[j] = *bp;
        kp += KD; qp += KD; vp += KD; gp += NH; bp += NH;
    }

#define SCAN_STEP(kc, qc, vcur, gc, bc)                                          \
    {                                                                            \
        float k0 = bf2f((kc)[0]), k1 = bf2f((kc)[1]);                            \
        float k2 = bf2f((kc)[2]), k3 = bf2f((kc)[3]);                            \
        float t1 = fmaf(s1, k1, s0 * k0);                                        \
        float t2 = fmaf(s3, k3, s2 * k2);                                        \
        float r  = t1 + t2;                                                      \
        /* off-chain: decayed state, ready before reduction finishes */          \
        float p0 = (gc) * s0, p1 = (gc) * s1, p2 = (gc) * s2, p3 = (gc) * s3;    \
        r += __shfl_xor(r, 2);  r += __shfl_xor(r, 4);  r += __shfl_xor(r, 8);   \
        r += __shfl_xor(r, 16); r += __shfl_xor(r, 32);                          \
        float u = (bc) * fmaf(-(gc), r, (vcur));                                 \
        s0 = fmaf(k0, u, p0); s1 = fmaf(k1, u, p1);                              \
        s2 = fmaf(k2, u, p2); s3 = fmaf(k3, u, p3);                              \
        float q0 = bf2f((qc)[0]), q1 = bf2f((qc)[1]);                            \
        float q2 = bf2f((qc)[2]), q3 = bf2f((qc)[3]);                            \
        float o1 = fmaf(s1, q1, s0 * q0);                                        \
        float o2 = fmaf(s3, q3, s2 * q2);                                        \
        float oo = o1 + o2;                                                      \
        oo += __shfl_xor(oo, 2);  oo += __shfl_xor(oo, 4);  oo += __shfl_xor(oo, 8); \
        oo += __shfl_xor(oo, 16); oo += __shfl_xor(oo, 32);                      \
        if (lane < 2) *op = f2bf(oo);                                            \
        op += KD;                                                                \
    }

    for (int t0 = 0; t0 < S_LEN - PF; t0 += PF) {
#pragma unroll
        for (int j = 0; j < PF; ++j) {
            short4v kc = kbuf[j], qc = qbuf[j];
            float vcur = bf2f(vbuf[j]);
            float gc = gbuf[j], bc = bbuf[j];
            // refill slot j (consumed PF steps from now) — issued before compute
            kbuf[j] = *(const short4v*)kp;
            qbuf[j] = *(const short4v*)qp;
            vbuf[j] = *vp; gbuf[j] = *gp; bbuf[j] = *bp;
            kp += KD; qp += KD; vp += KD; gp += NH; bp += NH;
            SCAN_STEP(kc, qc, vcur, gc, bc)
        }
    }
    // epilogue: last PF steps, no refill
#pragma unroll
    for (int j = 0; j < PF; ++j) {
        short4v kc = kbuf[j], qc = qbuf[j];
        float vcur = bf2f(vbuf[j]);
        float gc = gbuf[j], bc = bbuf[j];
        SCAN_STEP(kc, qc, vcur, gc, bc)
    }
#undef SCAN_STEP
}

// ---------------- RMSNorm + SiLU gate (bf16 in/out) ----------------
__global__ __launch_bounds__(256) void rms_gate_kernel(
    const short* __restrict__ o, const short* __restrict__ graw,
    const float* __restrict__ nw, short* __restrict__ og) {
    __shared__ float red[4];
    int m = blockIdx.x, t = threadIdx.x;
    short8 a = ((const short8*)(o + (size_t)m * VD))[t];
    float av[8];
#pragma unroll
    for (int i = 0; i < 8; ++i) av[i] = bf2f(a[i]);
    float ss = 0.f;
#pragma unroll
    for (int i = 0; i < 8; ++i) ss += av[i] * av[i];
#pragma unroll
    for (int off = 1; off < 64; off <<= 1) ss += __shfl_xor(ss, off);
    if ((t & 63) == 0) red[t >> 6] = ss;
    __syncthreads();
    float tot = red[0] + red[1] + red[2] + red[3];
    float sc = rsqrtf(tot * (1.f / VD) + 1e-6f);
    short8 gv = ((const short8*)(graw + (size_t)m * VD))[t];
    float4 n0 = ((const float4*)nw)[2 * t];
    float4 n1 = ((const float4*)nw)[2 * t + 1];
    const float* na = (const float*)&n0;
    const float* nb = (const float*)&n1;
    short8 ov;
#pragma unroll
    for (int i = 0; i < 4; ++i) ov[i]     = f2bf(av[i]     * sc * na[i] * silu_f(bf2f(gv[i])));
#pragma unroll
    for (int i = 0; i < 4; ++i) ov[i + 4] = f2bf(av[i + 4] * sc * nb[i] * silu_f(bf2f(gv[i + 4])));
    ((short8*)(og + (size_t)m * VD))[t] = ov;
}

// ---------------- host launcher ----------------
extern "C" void kernel_launch(void* const* d_in, const int* in_sizes, int n_in,
                              void* d_out, int out_size, void* d_ws, size_t ws_size,
                              hipStream_t stream) {
    const float* x    = (const float*)d_in[0];
    const float* Wq   = (const float*)d_in[1];
    const float* Wk   = (const float*)d_in[2];
    const float* Wv   = (const float*)d_in[3];
    const float* Wa   = (const float*)d_in[4];
    const float* Wb   = (const float*)d_in[5];
    const float* Wg   = (const float*)d_in[6];
    const float* Wo   = (const float*)d_in[7];
    const float* cwq  = (const float*)d_in[8];
    const float* cbq  = (const float*)d_in[9];
    const float* cwk  = (const float*)d_in[10];
    const float* cbk  = (const float*)d_in[11];
    const float* cwv  = (const float*)d_in[12];
    const float* cbv  = (const float*)d_in[13];
    const float* Alog = (const float*)d_in[14];
    const float* dtb  = (const float*)d_in[15];
    const float* nw   = (const float*)d_in[16];

    char* ws = (char*)d_ws;
    short* Wob = (short*)(ws);
    short* xb  = (short*)(ws + 8 * MB);
    short* Wqb = (short*)(ws + 24 * MB);
    short* Wkb = (short*)(ws + 32 * MB);
    short* Wvb = (short*)(ws + 40 * MB);
    short* Wgb = (short*)(ws + 48 * MB);
    short* qrb = (short*)(ws + 56 * MB);
    short* krb = (short*)(ws + 72 * MB);
    short* vrb = (short*)(ws + 88 * MB);
    short* grb = (short*)(ws + 104 * MB);
    short* qnb = (short*)(ws + 8 * MB);
    short* knb = (short*)(ws + 24 * MB);
    short* vnb = (short*)(ws + 40 * MB);
    float* gdec = (float*)(ws + 120 * MB);
    float* beta = (float*)(ws + 120 * MB + 262144);
    short* ob  = qrb;   // reuse
    short* ogb = krb;   // reuse

    // 1. fp32 -> bf16 conversions
    cvt_bf16_kernel<<<4096, 256, 0, stream>>>(x,  xb,  1048576);
    cvt_bf16_kernel<<<2048, 256, 0, stream>>>(Wq, Wqb, 524288);
    cvt_bf16_kernel<<<2048, 256, 0, stream>>>(Wk, Wkb, 524288);
    cvt_bf16_kernel<<<2048, 256, 0, stream>>>(Wv, Wvb, 524288);
    cvt_bf16_kernel<<<2048, 256, 0, stream>>>(Wg, Wgb, 524288);
    cvt_bf16_kernel<<<2048, 256, 0, stream>>>(Wo, Wob, 524288);

    // 2. a/b projection + decay/beta (fp32, small)
    ab_kernel<<<4096, 256, 0, stream>>>(x, Wa, Wb, Alog, dtb, gdec, beta);

    // 3. fused q/k/v/gate projections (bf16 MFMA), bf16 outputs
    gemm_qkvg<<<dim3(32, 16, 4), 256, 0, stream>>>(xb, Wqb, Wkb, Wvb, Wgb,
                                                   qrb, krb, vrb, grb);

    // 4. causal conv + SiLU + l2norm
    conv_kernel<<<16384, 256, 0, stream>>>(qrb, krb, vrb,
                                           cwq, cbq, cwk, cbk, cwv, cbv, qnb, knb, vnb);

    // 5. gated delta-rule scan
    scan_kernel<<<512, 256, 0, stream>>>(qnb, knb, vnb, gdec, beta, ob);

    // 6. RMSNorm + SiLU gate
    rms_gate_kernel<<<4096, 256, 0, stream>>>(ob, grb, nw, ogb);

    // 7. output projection (fp32 out)
    gemm_out<<<dim3(32, 16, 1), 256, 0, stream>>>(ogb, Wob, (float*)d_out);
}

// Round 4
// 845.971 us; speedup vs baseline: 2.0734x; 1.7364x over previous
//
#include <hip/hip_runtime.h>

// ---------------- problem constants ----------------
#define S_LEN   2048
#define NH      16
#define DIM     2048
#define KD      2048
#define VD      2048
#define MB      1048576ull
#define CT      64     // chunk length
#define NC      32     // chunks per sequence

typedef short  short8  __attribute__((ext_vector_type(8)));
typedef short  short4v __attribute__((ext_vector_type(4)));
typedef float  floatx4 __attribute__((ext_vector_type(4)));

#define MFMA(a, b, c) __builtin_amdgcn_mfma_f32_16x16x32_bf16((a), (b), (c), 0, 0, 0)

// fp32 -> bf16, round-to-nearest-even
__device__ inline short f2bf(float x) {
    unsigned u = __float_as_uint(x);
    unsigned r = (u + 0x7fffu + ((u >> 16) & 1u)) >> 16;
    return (short)r;
}
__device__ inline float bf2f(short s) {
    return __uint_as_float(((unsigned)(unsigned short)s) << 16);
}
__device__ inline float silu_f(float x) { return x / (1.f + __expf(-x)); }

__device__ inline short8 neg8(short8 a) {
    unsigned* p = (unsigned*)&a;
    p[0] ^= 0x80008000u; p[1] ^= 0x80008000u;
    p[2] ^= 0x80008000u; p[3] ^= 0x80008000u;
    return a;
}

// async global->LDS, 16B per lane; LDS dest is wave-uniform base (+lane*16 implicit)
__device__ inline void load_lds16(const void* g, void* l) {
    __builtin_amdgcn_global_load_lds(
        (const __attribute__((address_space(1))) unsigned int*)g,
        (__attribute__((address_space(3))) unsigned int*)l, 16, 0, 0);
}

// ---------------- fp32 -> bf16 conversion ----------------
__global__ __launch_bounds__(256) void cvt_bf16_kernel(const float* __restrict__ in,
                                                       short* __restrict__ out, int n8) {
    int i = blockIdx.x * 256 + threadIdx.x;
    if (i >= n8) return;
    float4 a = ((const float4*)in)[2 * i];
    float4 b = ((const float4*)in)[2 * i + 1];
    short8 o;
    o[0] = f2bf(a.x); o[1] = f2bf(a.y); o[2] = f2bf(a.z); o[3] = f2bf(a.w);
    o[4] = f2bf(b.x); o[5] = f2bf(b.y); o[6] = f2bf(b.z); o[7] = f2bf(b.w);
    ((short8*)out)[i] = o;
}

// ---------------- bf16 MFMA GEMM:  C[m,n] = sum_k A[m,k]*B[n,k] ----------------
__device__ inline void store_c(float* C, size_t idx, float v) { C[idx] = v; }
__device__ inline void store_c(short* C, size_t idx, float v) { C[idx] = f2bf(v); }

template <typename OutT>
__device__ inline void gemm_tile(const short* __restrict__ A, const short* __restrict__ Bw,
                                 OutT* __restrict__ C, int mtile, int ntile) {
    __shared__ short lA[128 * 32];
    __shared__ short lB[128 * 32];
    const int K = 2048, N = 2048;
    int t    = threadIdx.x;
    int wave = t >> 6;
    int lane = t & 63;
    int m0 = mtile * 128, n0 = ntile * 128;
    int wm = (wave & 1) * 64;
    int wn = (wave >> 1) * 64;

    floatx4 acc[4][4];
#pragma unroll
    for (int i = 0; i < 4; ++i)
#pragma unroll
        for (int j = 0; j < 4; ++j) acc[i][j] = (floatx4){0.f, 0.f, 0.f, 0.f};

    int fr = lane & 15;
    int fk = (lane >> 4) * 8;

    for (int k0 = 0; k0 < K; k0 += 32) {
#pragma unroll
        for (int p = 0; p < 2; ++p) {
            int c   = p * 256 + t;
            int row = c >> 2, kp = c & 3;
            const short* ga = A  + (size_t)(m0 + row) * K + k0 + kp * 8;
            const short* gb = Bw + (size_t)(n0 + row) * K + k0 + kp * 8;
            short* la = lA + (size_t)(p * 256 + wave * 64) * 8;
            short* lb = lB + (size_t)(p * 256 + wave * 64) * 8;
            load_lds16(ga, la);
            load_lds16(gb, lb);
        }
        __syncthreads();
        short8 af[4], bfr[4];
#pragma unroll
        for (int i = 0; i < 4; ++i) af[i]  = *(const short8*)(lA + (wm + i * 16 + fr) * 32 + fk);
#pragma unroll
        for (int j = 0; j < 4; ++j) bfr[j] = *(const short8*)(lB + (wn + j * 16 + fr) * 32 + fk);
#pragma unroll
        for (int i = 0; i < 4; ++i)
#pragma unroll
            for (int j = 0; j < 4; ++j)
                acc[i][j] = MFMA(af[i], bfr[j], acc[i][j]);
        __syncthreads();
    }
    int cr = (lane >> 4) * 4;
    int cc = lane & 15;
#pragma unroll
    for (int i = 0; i < 4; ++i)
#pragma unroll
        for (int j = 0; j < 4; ++j)
#pragma unroll
            for (int r = 0; r < 4; ++r)
                store_c(C, (size_t)(m0 + wm + i * 16 + cr + r) * N + (n0 + wn + j * 16 + cc),
                        acc[i][j][r]);
}

__global__ __launch_bounds__(256) void gemm_qkvg(const short* __restrict__ A,
    const short* __restrict__ B0, const short* __restrict__ B1,
    const short* __restrict__ B2, const short* __restrict__ B3,
    short* __restrict__ C0, short* __restrict__ C1,
    short* __restrict__ C2, short* __restrict__ C3) {
    const short* Bw; short* C;
    switch (blockIdx.z) {
        case 0:  Bw = B0; C = C0; break;
        case 1:  Bw = B1; C = C1; break;
        case 2:  Bw = B2; C = C2; break;
        default: Bw = B3; C = C3; break;
    }
    gemm_tile<short>(A, Bw, C, blockIdx.x, blockIdx.y);
}

__global__ __launch_bounds__(256) void gemm_out(const short* __restrict__ A,
    const short* __restrict__ Bw, float* __restrict__ C) {
    gemm_tile<float>(A, Bw, C, blockIdx.x, blockIdx.y);
}

// ---------------- a/b projection + decay/beta transform ----------------
__global__ __launch_bounds__(256) void ab_kernel(const float* __restrict__ x,
    const float* __restrict__ Wa, const float* __restrict__ Wb,
    const float* __restrict__ Alog, const float* __restrict__ dtb,
    float* __restrict__ gdec, float* __restrict__ beta) {
    __shared__ float xs[2048];
    __shared__ float red[32][9];
    int m = blockIdx.x, t = threadIdx.x;
    const float* xr = x + (size_t)m * DIM;
    for (int i = t; i < 512; i += 256) ((float4*)xs)[i] = ((const float4*)xr)[i];
    __syncthreads();
    int col = t >> 3, part = t & 7;
    const float* wr = (col < 16) ? (Wa + (size_t)col * DIM) : (Wb + (size_t)(col - 16) * DIM);
    float s = 0.f;
    int kb = part * 256;
#pragma unroll 4
    for (int k = 0; k < 256; k += 4) {
        float4 xv = *(const float4*)(xs + kb + k);
        float4 wv = *(const float4*)(wr + kb + k);
        s += xv.x * wv.x + xv.y * wv.y + xv.z * wv.z + xv.w * wv.w;
    }
    red[col][part] = s;
    __syncthreads();
    if (t < 32) {
        float a = 0.f;
#pragma unroll
        for (int p = 0; p < 8; ++p) a += red[t][p];
        if (t < 16) {
            float sp = a + dtb[t];
            float softp = (sp > 20.f) ? sp : log1pf(expf(sp));
            gdec[(size_t)m * NH + t] = expf(-expf(Alog[t]) * softp);
        } else {
            int h = t - 16;
            beta[(size_t)m * NH + h] = 1.f / (1.f + expf(-a));
        }
    }
}

// ---------------- causal conv (K=4) + SiLU + l2norm(q,k)  (bf16 in/out) ----------------
__global__ __launch_bounds__(256) void conv_kernel(
    const short* __restrict__ qr, const short* __restrict__ kr, const short* __restrict__ vr,
    const float* __restrict__ cwq, const float* __restrict__ cbq,
    const float* __restrict__ cwk, const float* __restrict__ cbk,
    const float* __restrict__ cwv, const float* __restrict__ cbv,
    short* __restrict__ qn, short* __restrict__ kn, short* __restrict__ vc) {
    int gw   = blockIdx.x * 4 + (threadIdx.x >> 6);
    int lane = threadIdx.x & 63;
    int h  = gw & (NH - 1);
    int m  = gw >> 4;
    int tt = m & (S_LEN - 1);
    int c  = h * 128 + lane * 2;
    size_t rowbase = (size_t)m * KD + c;

    float4 wq0 = ((const float4*)cwq)[c], wq1 = ((const float4*)cwq)[c + 1];
    float4 wk0 = ((const float4*)cwk)[c], wk1 = ((const float4*)cwk)[c + 1];
    float4 wv0 = ((const float4*)cwv)[c], wv1 = ((const float4*)cwv)[c + 1];
    float q0 = cbq[c], q1 = cbq[c + 1];
    float k0 = cbk[c], k1 = cbk[c + 1];
    float v0 = cbv[c], v1 = cbv[c + 1];
    const float* wq0a = (const float*)&wq0; const float* wq1a = (const float*)&wq1;
    const float* wk0a = (const float*)&wk0; const float* wk1a = (const float*)&wk1;
    const float* wv0a = (const float*)&wv0; const float* wv1a = (const float*)&wv1;
#pragma unroll
    for (int j = 0; j < 4; ++j) {
        int ts = tt - 3 + j;
        if (ts >= 0) {
            long long rb = (long long)rowbase + (long long)(j - 3) * KD;
            unsigned uq = *(const unsigned*)(qr + rb);
            unsigned uk = *(const unsigned*)(kr + rb);
            unsigned uv = *(const unsigned*)(vr + rb);
            q0 += bf2f((short)(uq & 0xffff)) * wq0a[j]; q1 += bf2f((short)(uq >> 16)) * wq1a[j];
            k0 += bf2f((short)(uk & 0xffff)) * wk0a[j]; k1 += bf2f((short)(uk >> 16)) * wk1a[j];
            v0 += bf2f((short)(uv & 0xffff)) * wv0a[j]; v1 += bf2f((short)(uv >> 16)) * wv1a[j];
        }
    }
    q0 = silu_f(q0); q1 = silu_f(q1);
    k0 = silu_f(k0); k1 = silu_f(k1);
    v0 = silu_f(v0); v1 = silu_f(v1);

    float sq = q0 * q0 + q1 * q1;
    float sk = k0 * k0 + k1 * k1;
#pragma unroll
    for (int off = 1; off < 64; off <<= 1) {
        sq += __shfl_xor(sq, off);
        sk += __shfl_xor(sk, off);
    }
    float iq = 1.f / fmaxf(sqrtf(sq), 1e-12f);
    float ik = 1.f / fmaxf(sqrtf(sk), 1e-12f);
    unsigned oq = (unsigned)(unsigned short)f2bf(q0 * iq) | ((unsigned)(unsigned short)f2bf(q1 * iq) << 16);
    unsigned ok = (unsigned)(unsigned short)f2bf(k0 * ik) | ((unsigned)(unsigned short)f2bf(k1 * ik) << 16);
    unsigned ov = (unsigned)(unsigned short)f2bf(v0)      | ((unsigned)(unsigned short)f2bf(v1)      << 16);
    *(unsigned*)(qn + rowbase) = oq;
    *(unsigned*)(kn + rowbase) = ok;
    *(unsigned*)(vc + rowbase) = ov;
}

// ---------------- chunked delta-rule: per-chunk solve  ----------------
// WG = (bh, chunk, half). half0: UvT = (I+A)^{-1} diag(beta) V  (stored transposed [v][t])
//                         half1: Tk  = (I+A)^{-1} diag(beta*e^L) K  (stored natural [t][dk])
// A[t,i] = beta_t e^{L_t-L_i} (k_t.k_i), i<t.  (I+A)^{-1} = prod (I + (-A)^{2^j}).
__global__ __launch_bounds__(256) void solve_kernel(
    const short* __restrict__ kn, const short* __restrict__ vn,
    const float* __restrict__ gdec, const float* __restrict__ beta,
    short* __restrict__ UvT, short* __restrict__ Tk) {
    __shared__ short Pn[64][72];
    __shared__ short Pt[64][72];
    __shared__ short UT[128][72];
    __shared__ float Ls[64];
    __shared__ float Bs[64];

    int wg   = blockIdx.x;
    int half = wg & 1;
    int c    = (wg >> 1) & 31;
    int bh   = wg >> 6;
    int b = bh >> 4, h = bh & 15;
    int tid = threadIdx.x;
    int wave = tid >> 6, lane = tid & 63;
    int quad = lane >> 4, l16 = lane & 15;

    const short* Kb = kn + ((size_t)(b * S_LEN + c * CT)) * KD + h * 128;
    const short* Vb = vn + ((size_t)(b * S_LEN + c * CT)) * KD + h * 128;

    if (wave == 0) {
        float lg = __logf(gdec[((size_t)(b * S_LEN + c * CT) + lane) * NH + h]);
#pragma unroll
        for (int off = 1; off < 64; off <<= 1) {
            float y = __shfl_up(lg, off);
            if (lane >= off) lg += y;
        }
        Ls[lane] = lg;
        Bs[lane] = beta[((size_t)(b * S_LEN + c * CT) + lane) * NH + h];
    }
    __syncthreads();

    // build P = -A
    {
        floatx4 acc[4];
#pragma unroll
        for (int i = 0; i < 4; ++i) acc[i] = (floatx4){0.f, 0.f, 0.f, 0.f};
        for (int ks = 0; ks < 4; ++ks) {
            short8 af = *(const short8*)(Kb + (size_t)(wave * 16 + l16) * KD + ks * 32 + quad * 8);
#pragma unroll
            for (int it = 0; it < 4; ++it) {
                short8 bf = *(const short8*)(Kb + (size_t)(it * 16 + l16) * KD + ks * 32 + quad * 8);
                acc[it] = MFMA(af, bf, acc[it]);
            }
        }
#pragma unroll
        for (int it = 0; it < 4; ++it) {
            int icol = it * 16 + l16;
#pragma unroll
            for (int r = 0; r < 4; ++r) {
                int trow = wave * 16 + quad * 4 + r;
                float v = 0.f;
                if (icol < trow) v = -Bs[trow] * __expf(Ls[trow] - Ls[icol]) * acc[it][r];
                short bv = f2bf(v);
                Pn[trow][icol] = bv;
                Pt[icol][trow] = bv;
            }
        }
    }

    // RHS -> UT (transposed [n][t])
    {
        const short* src = half ? Kb : Vb;
        int tr = tid >> 2, seg = (tid & 3) * 32;
        float s = Bs[tr] * (half ? __expf(Ls[tr]) : 1.f);
#pragma unroll
        for (int j = 0; j < 4; ++j) {
            short8 d = *(const short8*)(src + (size_t)tr * KD + seg + j * 8);
#pragma unroll
            for (int e = 0; e < 8; ++e)
                UT[seg + j * 8 + e][tr] = f2bf(bf2f(d[e]) * s);
        }
    }
    __syncthreads();

    // 6 applications U <- U + P U, squaring P between
    for (int iter = 0; iter < 6; ++iter) {
        floatx4 acc[8];
#pragma unroll
        for (int nt = 0; nt < 8; ++nt) {
            short4v u4 = *(const short4v*)&UT[nt * 16 + l16][wave * 16 + quad * 4];
            floatx4 a;
#pragma unroll
            for (int e = 0; e < 4; ++e) a[e] = bf2f(u4[e]);
            acc[nt] = a;
        }
        for (int ks = 0; ks < 2; ++ks) {
            short8 af = *(const short8*)&Pn[wave * 16 + l16][ks * 32 + quad * 8];
#pragma unroll
            for (int nt = 0; nt < 8; ++nt) {
                short8 bf = *(const short8*)&UT[nt * 16 + l16][ks * 32 + quad * 8];
                acc[nt] = MFMA(af, bf, acc[nt]);
            }
        }
        __syncthreads();
        if (iter < 5) {
#pragma unroll
            for (int nt = 0; nt < 8; ++nt) {
                short4v w4;
#pragma unroll
                for (int e = 0; e < 4; ++e) w4[e] = f2bf(acc[nt][e]);
                *(short4v*)&UT[nt * 16 + l16][wave * 16 + quad * 4] = w4;
            }
            floatx4 pacc[4];
#pragma unroll
            for (int it = 0; it < 4; ++it) pacc[it] = (floatx4){0.f, 0.f, 0.f, 0.f};
            for (int ks = 0; ks < 2; ++ks) {
                short8 paf = *(const short8*)&Pn[wave * 16 + l16][ks * 32 + quad * 8];
#pragma unroll
                for (int it = 0; it < 4; ++it) {
                    short8 pbf = *(const short8*)&Pt[it * 16 + l16][ks * 32 + quad * 8];
                    pacc[it] = MFMA(paf, pbf, pacc[it]);
                }
            }
            __syncthreads();
#pragma unroll
            for (int it = 0; it < 4; ++it) {
                int icol = it * 16 + l16;
#pragma unroll
                for (int r = 0; r < 4; ++r) {
                    int trow = wave * 16 + quad * 4 + r;
                    short bv = f2bf(pacc[it][r]);
                    Pn[trow][icol] = bv;
                    Pt[icol][trow] = bv;
                }
            }
            __syncthreads();
        } else {
            size_t cb = (size_t)(bh * NC + c);
            if (half == 0) {
#pragma unroll
                for (int nt = 0; nt < 8; ++nt) {
                    short4v w4;
#pragma unroll
                    for (int e = 0; e < 4; ++e) w4[e] = f2bf(acc[nt][e]);
                    *(short4v*)(UvT + (cb * 128 + nt * 16 + l16) * 64 + wave * 16 + quad * 4) = w4;
                }
            } else {
#pragma unroll
                for (int nt = 0; nt < 8; ++nt)
#pragma unroll
                    for (int r = 0; r < 4; ++r)
                        Tk[(cb * 64 + wave * 16 + quad * 4 + r) * 128 + nt * 16 + l16] = f2bf(acc[nt][r]);
            }
        }
    }
}

// ---------------- chunk prep B: W, Qg, KtilT, gam63 ----------------
__global__ __launch_bounds__(256) void prepb_kernel(
    const short* __restrict__ qn, const short* __restrict__ kn,
    const float* __restrict__ gdec,
    short* __restrict__ Wb_, short* __restrict__ Qg,
    short* __restrict__ KtT, float* __restrict__ gam63) {
    __shared__ short KT[128][72];
    __shared__ float Ls[64];
    int wg = blockIdx.x;
    int c = wg & 31, bh = wg >> 5;
    int b = bh >> 4, h = bh & 15;
    int tid = threadIdx.x, wave = tid >> 6, lane = tid & 63;
    int quad = lane >> 4, l16 = lane & 15;
    const short* Qb = qn + ((size_t)(b * S_LEN + c * CT)) * KD + h * 128;
    const short* Kb = kn + ((size_t)(b * S_LEN + c * CT)) * KD + h * 128;

    if (wave == 0) {
        float lg = __logf(gdec[((size_t)(b * S_LEN + c * CT) + lane) * NH + h]);
#pragma unroll
        for (int off = 1; off < 64; off <<= 1) {
            float y = __shfl_up(lg, off);
            if (lane >= off) lg += y;
        }
        Ls[lane] = lg;
    }
    __syncthreads();
    size_t cb = (size_t)(bh * NC + c);
    if (tid == 0) gam63[cb] = __expf(Ls[63]);

    // W = mask_{i<=t} e^{L_t-L_i} (q_t.k_i)
    {
        floatx4 acc[4];
#pragma unroll
        for (int i = 0; i < 4; ++i) acc[i] = (floatx4){0.f, 0.f, 0.f, 0.f};
        for (int ks = 0; ks < 4; ++ks) {
            short8 af = *(const short8*)(Qb + (size_t)(wave * 16 + l16) * KD + ks * 32 + quad * 8);
#pragma unroll
            for (int it = 0; it < 4; ++it) {
                short8 bf = *(const short8*)(Kb + (size_t)(it * 16 + l16) * KD + ks * 32 + quad * 8);
                acc[it] = MFMA(af, bf, acc[it]);
            }
        }
#pragma unroll
        for (int it = 0; it < 4; ++it) {
            int icol = it * 16 + l16;
#pragma unroll
            for (int r = 0; r < 4; ++r) {
                int trow = wave * 16 + quad * 4 + r;
                float v = (icol <= trow) ? __expf(Ls[trow] - Ls[icol]) * acc[it][r] : 0.f;
                Wb_[(cb * 64 + trow) * 64 + icol] = f2bf(v);
            }
        }
    }

    // Qg rows (e^{L_t} q_t)  +  stage scaled-K transpose
    {
        int tr = tid >> 2, seg = (tid & 3) * 32;
        float sq = __expf(Ls[tr]);
        float sk = __expf(Ls[63] - Ls[tr]);
#pragma unroll
        for (int j = 0; j < 4; ++j) {
            short8 dq = *(const short8*)(Qb + (size_t)tr * KD + seg + j * 8);
            short8 dk = *(const short8*)(Kb + (size_t)tr * KD + seg + j * 8);
            short8 oq;
#pragma unroll
            for (int e = 0; e < 8; ++e) {
                oq[e] = f2bf(bf2f(dq[e]) * sq);
                KT[seg + j * 8 + e][tr] = f2bf(bf2f(dk[e]) * sk);
            }
            *(short8*)(Qg + (cb * 64 + tr) * 128 + seg + j * 8) = oq;
        }
    }
    __syncthreads();
    {
        int dk = tid >> 1, seg = (tid & 1) * 32;
#pragma unroll
        for (int j = 0; j < 4; ++j) {
            short8 v = *(const short8*)&KT[dk][seg + j * 8];
            *(short8*)(KtT + (cb * 128 + dk) * 64 + seg + j * 8) = v;
        }
    }
}

// ---------------- sequential chunk pass: state + outputs ----------------
// WG = (bh, vhalf). fp32 state in regs (sacc) + bf16 operand copy in LDS (ST, v-major).
__global__ __launch_bounds__(256) void seq_kernel(
    const short* __restrict__ UvT, const short* __restrict__ Tk,
    const short* __restrict__ Wb_, const short* __restrict__ Qg,
    const short* __restrict__ KtT, const float* __restrict__ gam63,
    short* __restrict__ ob) {
    __shared__ short ST[64][136];
    __shared__ short UTs[64][72];
    int wg = blockIdx.x;
    int vh = wg & 1, bh = wg >> 1;
    int b = bh >> 4, h = bh & 15;
    int tid = threadIdx.x, wave = tid >> 6, lane = tid & 63;
    int quad = lane >> 4, l16 = lane & 15;

    for (int i = tid; i < 64 * 136; i += 256) ((short*)ST)[i] = 0;
    floatx4 sacc[8];
#pragma unroll
    for (int i = 0; i < 8; ++i) sacc[i] = (floatx4){0.f, 0.f, 0.f, 0.f};
    __syncthreads();

    for (int c = 0; c < NC; ++c) {
        size_t cb = (size_t)(bh * NC + c);
        const short* Tkc = Tk + cb * 64 * 128;
        const short* Uvc = UvT + (cb * 128 + (size_t)vh * 64) * 64;
        const short* Qgc = Qg + cb * 64 * 128;
        const short* Wc  = Wb_ + cb * 64 * 64;
        const short* Ktc = KtT + cb * 128 * 64;
        float gam = gam63[cb];

        // step1: U = Uv - Tk*S ; step2a: O = Qg*S
        floatx4 uacc[4], oacc[4];
#pragma unroll
        for (int vt = 0; vt < 4; ++vt) {
            short4v u4 = *(const short4v*)(Uvc + (size_t)(vt * 16 + l16) * 64 + wave * 16 + quad * 4);
            floatx4 a;
#pragma unroll
            for (int e = 0; e < 4; ++e) a[e] = bf2f(u4[e]);
            uacc[vt] = a;
            oacc[vt] = (floatx4){0.f, 0.f, 0.f, 0.f};
        }
        for (int ks = 0; ks < 4; ++ks) {
            short8 afT = neg8(*(const short8*)(Tkc + (size_t)(wave * 16 + l16) * 128 + ks * 32 + quad * 8));
            short8 afQ = *(const short8*)(Qgc + (size_t)(wave * 16 + l16) * 128 + ks * 32 + quad * 8);
#pragma unroll
            for (int vt = 0; vt < 4; ++vt) {
                short8 bf = *(const short8*)&ST[vt * 16 + l16][ks * 32 + quad * 8];
                uacc[vt] = MFMA(afT, bf, uacc[vt]);
                oacc[vt] = MFMA(afQ, bf, oacc[vt]);
            }
        }
#pragma unroll
        for (int vt = 0; vt < 4; ++vt) {
            short4v w4;
#pragma unroll
            for (int e = 0; e < 4; ++e) w4[e] = f2bf(uacc[vt][e]);
            *(short4v*)&UTs[vt * 16 + l16][wave * 16 + quad * 4] = w4;
        }
        __syncthreads();  // ST reads done; UTs visible

        // step2b: O += W*U ; write O
        for (int ks = 0; ks < 2; ++ks) {
            short8 af = *(const short8*)(Wc + (size_t)(wave * 16 + l16) * 64 + ks * 32 + quad * 8);
#pragma unroll
            for (int vt = 0; vt < 4; ++vt) {
                short8 bf = *(const short8*)&UTs[vt * 16 + l16][ks * 32 + quad * 8];
                oacc[vt] = MFMA(af, bf, oacc[vt]);
            }
        }
#pragma unroll
        for (int vt = 0; vt < 4; ++vt)
#pragma unroll
            for (int r = 0; r < 4; ++r) {
                int m = b * S_LEN + c * CT + wave * 16 + quad * 4 + r;
                ob[(size_t)m * VD + h * 128 + vh * 64 + vt * 16 + l16] = f2bf(oacc[vt][r]);
            }

        // step3: S = gam*S + Ktil^T U
#pragma unroll
        for (int dt = 0; dt < 8; ++dt)
#pragma unroll
            for (int e = 0; e < 4; ++e) sacc[dt][e] *= gam;
        for (int ks = 0; ks < 2; ++ks) {
            short8 af = *(const short8*)&UTs[wave * 16 + l16][ks * 32 + quad * 8];
#pragma unroll
            for (int dt = 0; dt < 8; ++dt) {
                short8 bf = *(const short8*)(Ktc + (size_t)(dt * 16 + l16) * 64 + ks * 32 + quad * 8);
                sacc[dt] = MFMA(af, bf, sacc[dt]);
            }
        }
#pragma unroll
        for (int dt = 0; dt < 8; ++dt)
#pragma unroll
            for (int r = 0; r < 4; ++r)
                ST[wave * 16 + quad * 4 + r][dt * 16 + l16] = f2bf(sacc[dt][r]);
        __syncthreads();  // ST writes visible for next chunk
    }
}

// ---------------- RMSNorm + SiLU gate (bf16 in/out) ----------------
__global__ __launch_bounds__(256) void rms_gate_kernel(
    const short* __restrict__ o, const short* __restrict__ graw,
    const float* __restrict__ nw, short* __restrict__ og) {
    __shared__ float red[4];
    int m = blockIdx.x, t = threadIdx.x;
    short8 a = ((const short8*)(o + (size_t)m * VD))[t];
    float av[8];
#pragma unroll
    for (int i = 0; i < 8; ++i) av[i] = bf2f(a[i]);
    float ss = 0.f;
#pragma unroll
    for (int i = 0; i < 8; ++i) ss += av[i] * av[i];
#pragma unroll
    for (int off = 1; off < 64; off <<= 1) ss += __shfl_xor(ss, off);
    if ((t & 63) == 0) red[t >> 6] = ss;
    __syncthreads();
    float tot = red[0] + red[1] + red[2] + red[3];
    float sc = rsqrtf(tot * (1.f / VD) + 1e-6f);
    short8 gv = ((const short8*)(graw + (size_t)m * VD))[t];
    float4 n0 = ((const float4*)nw)[2 * t];
    float4 n1 = ((const float4*)nw)[2 * t + 1];
    const float* na = (const float*)&n0;
    const float* nb = (const float*)&n1;
    short8 ov;
#pragma unroll
    for (int i = 0; i < 4; ++i) ov[i]     = f2bf(av[i]     * sc * na[i] * silu_f(bf2f(gv[i])));
#pragma unroll
    for (int i = 0; i < 4; ++i) ov[i + 4] = f2bf(av[i + 4] * sc * nb[i] * silu_f(bf2f(gv[i + 4])));
    ((short8*)(og + (size_t)m * VD))[t] = ov;
}

// ---------------- host launcher ----------------
extern "C" void kernel_launch(void* const* d_in, const int* in_sizes, int n_in,
                              void* d_out, int out_size, void* d_ws, size_t ws_size,
                              hipStream_t stream) {
    const float* x    = (const float*)d_in[0];
    const float* Wq   = (const float*)d_in[1];
    const float* Wk   = (const float*)d_in[2];
    const float* Wv   = (const float*)d_in[3];
    const float* Wa   = (const float*)d_in[4];
    const float* Wb   = (const float*)d_in[5];
    const float* Wg   = (const float*)d_in[6];
    const float* Wo   = (const float*)d_in[7];
    const float* cwq  = (const float*)d_in[8];
    const float* cbq  = (const float*)d_in[9];
    const float* cwk  = (const float*)d_in[10];
    const float* cbk  = (const float*)d_in[11];
    const float* cwv  = (const float*)d_in[12];
    const float* cbv  = (const float*)d_in[13];
    const float* Alog = (const float*)d_in[14];
    const float* dtb  = (const float*)d_in[15];
    const float* nw   = (const float*)d_in[16];

    char* ws = (char*)d_ws;
    short* Wob = (short*)(ws);
    short* xb  = (short*)(ws + 8 * MB);
    short* Wqb = (short*)(ws + 24 * MB);
    short* Wkb = (short*)(ws + 32 * MB);
    short* Wvb = (short*)(ws + 40 * MB);
    short* Wgb = (short*)(ws + 48 * MB);
    short* qrb = (short*)(ws + 56 * MB);
    short* krb = (short*)(ws + 72 * MB);
    short* vrb = (short*)(ws + 88 * MB);
    short* grb = (short*)(ws + 104 * MB);
    short* qnb = (short*)(ws + 8 * MB);
    short* knb = (short*)(ws + 24 * MB);
    short* vnb = (short*)(ws + 40 * MB);
    float* gdec = (float*)(ws + 120 * MB);
    float* beta = (float*)(ws + 120 * MB + 262144);
    short* ob  = qrb;   // reuse
    short* ogb = krb;   // reuse
    // chunked-scan buffers
    short* UvT  = (short*)(ws + 121 * MB);   // [1024][128][64]
    short* Tkb  = (short*)(ws + 137 * MB);   // [1024][64][128]
    short* Wbuf = (short*)(ws + 153 * MB);   // [1024][64][64]
    short* Qgb  = (short*)(ws + 161 * MB);   // [1024][64][128]
    short* KtT  = (short*)(ws + 177 * MB);   // [1024][128][64]
    float* gm63 = (float*)(ws + 193 * MB);   // [1024]

    // 1. fp32 -> bf16 conversions
    cvt_bf16_kernel<<<4096, 256, 0, stream>>>(x,  xb,  1048576);
    cvt_bf16_kernel<<<2048, 256, 0, stream>>>(Wq, Wqb, 524288);
    cvt_bf16_kernel<<<2048, 256, 0, stream>>>(Wk, Wkb, 524288);
    cvt_bf16_kernel<<<2048, 256, 0, stream>>>(Wv, Wvb, 524288);
    cvt_bf16_kernel<<<2048, 256, 0, stream>>>(Wg, Wgb, 524288);
    cvt_bf16_kernel<<<2048, 256, 0, stream>>>(Wo, Wob, 524288);

    // 2. a/b projection + decay/beta
    ab_kernel<<<4096, 256, 0, stream>>>(x, Wa, Wb, Alog, dtb, gdec, beta);

    // 3. fused q/k/v/gate projections
    gemm_qkvg<<<dim3(32, 16, 4), 256, 0, stream>>>(xb, Wqb, Wkb, Wvb, Wgb,
                                                   qrb, krb, vrb, grb);

    // 4. causal conv + SiLU + l2norm
    conv_kernel<<<16384, 256, 0, stream>>>(qrb, krb, vrb,
                                           cwq, cbq, cwk, cbk, cwv, cbv, qnb, knb, vnb);

    // 5. chunked delta-rule
    solve_kernel<<<2048, 256, 0, stream>>>(knb, vnb, gdec, beta, UvT, Tkb);
    prepb_kernel<<<1024, 256, 0, stream>>>(qnb, knb, gdec, Wbuf, Qgb, KtT, gm63);
    seq_kernel<<<64, 256, 0, stream>>>(UvT, Tkb, Wbuf, Qgb, KtT, gm63, ob);

    // 6. RMSNorm + SiLU gate
    rms_gate_kernel<<<4096, 256, 0, stream>>>(ob, grb, nw, ogb);

    // 7. output projection
    gemm_out<<<dim3(32, 16, 1), 256, 0, stream>>>(ogb, Wob, (float*)d_out);
}

// Round 5
// 782.852 us; speedup vs baseline: 2.2405x; 1.0806x over previous
//
#include <hip/hip_runtime.h>

// ---------------- problem constants ----------------
#define S_LEN   2048
#define NH      16
#define DIM     2048
#define KD      2048
#define VD      2048
#define MB      1048576ull
#define CT      64     // chunk length
#define NC      32     // chunks per sequence

typedef short  short8  __attribute__((ext_vector_type(8)));
typedef short  short4v __attribute__((ext_vector_type(4)));
typedef float  floatx4 __attribute__((ext_vector_type(4)));

#define MFMA(a, b, c) __builtin_amdgcn_mfma_f32_16x16x32_bf16((a), (b), (c), 0, 0, 0)

// fp32 -> bf16, round-to-nearest-even
__device__ inline short f2bf(float x) {
    unsigned u = __float_as_uint(x);
    unsigned r = (u + 0x7fffu + ((u >> 16) & 1u)) >> 16;
    return (short)r;
}
__device__ inline float bf2f(short s) {
    return __uint_as_float(((unsigned)(unsigned short)s) << 16);
}
__device__ inline float silu_f(float x) { return x / (1.f + __expf(-x)); }

__device__ inline short8 neg8(short8 a) {
    unsigned* p = (unsigned*)&a;
    p[0] ^= 0x80008000u; p[1] ^= 0x80008000u;
    p[2] ^= 0x80008000u; p[3] ^= 0x80008000u;
    return a;
}

// async global->LDS, 16B per lane; LDS dest is wave-uniform base (+lane*16 implicit)
__device__ inline void load_lds16(const void* g, void* l) {
    __builtin_amdgcn_global_load_lds(
        (const __attribute__((address_space(1))) unsigned int*)g,
        (__attribute__((address_space(3))) unsigned int*)l, 16, 0, 0);
}

// ---------------- fp32 -> bf16 conversion (all 6 tensors, one launch) ----------------
__global__ __launch_bounds__(256) void cvt_all_kernel(
    const float* __restrict__ x,  const float* __restrict__ Wq,
    const float* __restrict__ Wk, const float* __restrict__ Wv,
    const float* __restrict__ Wg, const float* __restrict__ Wo,
    short* __restrict__ xb,  short* __restrict__ Wqb, short* __restrict__ Wkb,
    short* __restrict__ Wvb, short* __restrict__ Wgb, short* __restrict__ Wob) {
    const float* in; short* out; int n8;
    switch (blockIdx.y) {
        case 0:  in = x;  out = xb;  n8 = 1048576; break;
        case 1:  in = Wq; out = Wqb; n8 = 524288;  break;
        case 2:  in = Wk; out = Wkb; n8 = 524288;  break;
        case 3:  in = Wv; out = Wvb; n8 = 524288;  break;
        case 4:  in = Wg; out = Wgb; n8 = 524288;  break;
        default: in = Wo; out = Wob; n8 = 524288;  break;
    }
    int i = blockIdx.x * 256 + threadIdx.x;
    if (i >= n8) return;
    float4 a = ((const float4*)in)[2 * i];
    float4 b = ((const float4*)in)[2 * i + 1];
    short8 o;
    o[0] = f2bf(a.x); o[1] = f2bf(a.y); o[2] = f2bf(a.z); o[3] = f2bf(a.w);
    o[4] = f2bf(b.x); o[5] = f2bf(b.y); o[6] = f2bf(b.z); o[7] = f2bf(b.w);
    ((short8*)out)[i] = o;
}

// ---------------- bf16 MFMA GEMM:  C[m,n] = sum_k A[m,k]*B[n,k] ----------------
__device__ inline void store_c(float* C, size_t idx, float v) { C[idx] = v; }
__device__ inline void store_c(short* C, size_t idx, float v) { C[idx] = f2bf(v); }

template <typename OutT>
__device__ inline void gemm_tile(const short* __restrict__ A, const short* __restrict__ Bw,
                                 OutT* __restrict__ C, int mtile, int ntile) {
    __shared__ short lA[128 * 32];
    __shared__ short lB[128 * 32];
    const int K = 2048, N = 2048;
    int t    = threadIdx.x;
    int wave = t >> 6;
    int lane = t & 63;
    int m0 = mtile * 128, n0 = ntile * 128;
    int wm = (wave & 1) * 64;
    int wn = (wave >> 1) * 64;

    floatx4 acc[4][4];
#pragma unroll
    for (int i = 0; i < 4; ++i)
#pragma unroll
        for (int j = 0; j < 4; ++j) acc[i][j] = (floatx4){0.f, 0.f, 0.f, 0.f};

    int fr = lane & 15;
    int fk = (lane >> 4) * 8;

    for (int k0 = 0; k0 < K; k0 += 32) {
#pragma unroll
        for (int p = 0; p < 2; ++p) {
            int c   = p * 256 + t;
            int row = c >> 2, kp = c & 3;
            const short* ga = A  + (size_t)(m0 + row) * K + k0 + kp * 8;
            const short* gb = Bw + (size_t)(n0 + row) * K + k0 + kp * 8;
            short* la = lA + (size_t)(p * 256 + wave * 64) * 8;
            short* lb = lB + (size_t)(p * 256 + wave * 64) * 8;
            load_lds16(ga, la);
            load_lds16(gb, lb);
        }
        __syncthreads();
        short8 af[4], bfr[4];
#pragma unroll
        for (int i = 0; i < 4; ++i) af[i]  = *(const short8*)(lA + (wm + i * 16 + fr) * 32 + fk);
#pragma unroll
        for (int j = 0; j < 4; ++j) bfr[j] = *(const short8*)(lB + (wn + j * 16 + fr) * 32 + fk);
#pragma unroll
        for (int i = 0; i < 4; ++i)
#pragma unroll
            for (int j = 0; j < 4; ++j)
                acc[i][j] = MFMA(af[i], bfr[j], acc[i][j]);
        __syncthreads();
    }
    int cr = (lane >> 4) * 4;
    int cc = lane & 15;
#pragma unroll
    for (int i = 0; i < 4; ++i)
#pragma unroll
        for (int j = 0; j < 4; ++j)
#pragma unroll
            for (int r = 0; r < 4; ++r)
                store_c(C, (size_t)(m0 + wm + i * 16 + cr + r) * N + (n0 + wn + j * 16 + cc),
                        acc[i][j][r]);
}

__global__ __launch_bounds__(256) void gemm_qkvg(const short* __restrict__ A,
    const short* __restrict__ B0, const short* __restrict__ B1,
    const short* __restrict__ B2, const short* __restrict__ B3,
    short* __restrict__ C0, short* __restrict__ C1,
    short* __restrict__ C2, short* __restrict__ C3) {
    const short* Bw; short* C;
    switch (blockIdx.z) {
        case 0:  Bw = B0; C = C0; break;
        case 1:  Bw = B1; C = C1; break;
        case 2:  Bw = B2; C = C2; break;
        default: Bw = B3; C = C3; break;
    }
    gemm_tile<short>(A, Bw, C, blockIdx.x, blockIdx.y);
}

__global__ __launch_bounds__(256) void gemm_out(const short* __restrict__ A,
    const short* __restrict__ Bw, float* __restrict__ C) {
    gemm_tile<float>(A, Bw, C, blockIdx.x, blockIdx.y);
}

// ---------------- a/b projection + decay/beta transform ----------------
__global__ __launch_bounds__(256) void ab_kernel(const float* __restrict__ x,
    const float* __restrict__ Wa, const float* __restrict__ Wb,
    const float* __restrict__ Alog, const float* __restrict__ dtb,
    float* __restrict__ gdec, float* __restrict__ beta) {
    __shared__ float xs[2048];
    __shared__ float red[32][9];
    int m = blockIdx.x, t = threadIdx.x;
    const float* xr = x + (size_t)m * DIM;
    for (int i = t; i < 512; i += 256) ((float4*)xs)[i] = ((const float4*)xr)[i];
    __syncthreads();
    int col = t >> 3, part = t & 7;
    const float* wr = (col < 16) ? (Wa + (size_t)col * DIM) : (Wb + (size_t)(col - 16) * DIM);
    float s = 0.f;
    int kb = part * 256;
#pragma unroll 4
    for (int k = 0; k < 256; k += 4) {
        float4 xv = *(const float4*)(xs + kb + k);
        float4 wv = *(const float4*)(wr + kb + k);
        s += xv.x * wv.x + xv.y * wv.y + xv.z * wv.z + xv.w * wv.w;
    }
    red[col][part] = s;
    __syncthreads();
    if (t < 32) {
        float a = 0.f;
#pragma unroll
        for (int p = 0; p < 8; ++p) a += red[t][p];
        if (t < 16) {
            float sp = a + dtb[t];
            float softp = (sp > 20.f) ? sp : log1pf(expf(sp));
            gdec[(size_t)m * NH + t] = expf(-expf(Alog[t]) * softp);
        } else {
            int h = t - 16;
            beta[(size_t)m * NH + h] = 1.f / (1.f + expf(-a));
        }
    }
}

// ---------------- causal conv (K=4) + SiLU + l2norm(q,k)  (bf16 in/out) ----------------
__global__ __launch_bounds__(256) void conv_kernel(
    const short* __restrict__ qr, const short* __restrict__ kr, const short* __restrict__ vr,
    const float* __restrict__ cwq, const float* __restrict__ cbq,
    const float* __restrict__ cwk, const float* __restrict__ cbk,
    const float* __restrict__ cwv, const float* __restrict__ cbv,
    short* __restrict__ qn, short* __restrict__ kn, short* __restrict__ vc) {
    int gw   = blockIdx.x * 4 + (threadIdx.x >> 6);
    int lane = threadIdx.x & 63;
    int h  = gw & (NH - 1);
    int m  = gw >> 4;
    int tt = m & (S_LEN - 1);
    int c  = h * 128 + lane * 2;
    size_t rowbase = (size_t)m * KD + c;

    float4 wq0 = ((const float4*)cwq)[c], wq1 = ((const float4*)cwq)[c + 1];
    float4 wk0 = ((const float4*)cwk)[c], wk1 = ((const float4*)cwk)[c + 1];
    float4 wv0 = ((const float4*)cwv)[c], wv1 = ((const float4*)cwv)[c + 1];
    float q0 = cbq[c], q1 = cbq[c + 1];
    float k0 = cbk[c], k1 = cbk[c + 1];
    float v0 = cbv[c], v1 = cbv[c + 1];
    const float* wq0a = (const float*)&wq0; const float* wq1a = (const float*)&wq1;
    const float* wk0a = (const float*)&wk0; const float* wk1a = (const float*)&wk1;
    const float* wv0a = (const float*)&wv0; const float* wv1a = (const float*)&wv1;
#pragma unroll
    for (int j = 0; j < 4; ++j) {
        int ts = tt - 3 + j;
        if (ts >= 0) {
            long long rb = (long long)rowbase + (long long)(j - 3) * KD;
            unsigned uq = *(const unsigned*)(qr + rb);
            unsigned uk = *(const unsigned*)(kr + rb);
            unsigned uv = *(const unsigned*)(vr + rb);
            q0 += bf2f((short)(uq & 0xffff)) * wq0a[j]; q1 += bf2f((short)(uq >> 16)) * wq1a[j];
            k0 += bf2f((short)(uk & 0xffff)) * wk0a[j]; k1 += bf2f((short)(uk >> 16)) * wk1a[j];
            v0 += bf2f((short)(uv & 0xffff)) * wv0a[j]; v1 += bf2f((short)(uv >> 16)) * wv1a[j];
        }
    }
    q0 = silu_f(q0); q1 = silu_f(q1);
    k0 = silu_f(k0); k1 = silu_f(k1);
    v0 = silu_f(v0); v1 = silu_f(v1);

    float sq = q0 * q0 + q1 * q1;
    float sk = k0 * k0 + k1 * k1;
#pragma unroll
    for (int off = 1; off < 64; off <<= 1) {
        sq += __shfl_xor(sq, off);
        sk += __shfl_xor(sk, off);
    }
    float iq = 1.f / fmaxf(sqrtf(sq), 1e-12f);
    float ik = 1.f / fmaxf(sqrtf(sk), 1e-12f);
    unsigned oq = (unsigned)(unsigned short)f2bf(q0 * iq) | ((unsigned)(unsigned short)f2bf(q1 * iq) << 16);
    unsigned ok = (unsigned)(unsigned short)f2bf(k0 * ik) | ((unsigned)(unsigned short)f2bf(k1 * ik) << 16);
    unsigned ov = (unsigned)(unsigned short)f2bf(v0)      | ((unsigned)(unsigned short)f2bf(v1)      << 16);
    *(unsigned*)(qn + rowbase) = oq;
    *(unsigned*)(kn + rowbase) = ok;
    *(unsigned*)(vc + rowbase) = ov;
}

// ---------------- chunked delta-rule: per-chunk solve  ----------------
__global__ __launch_bounds__(256) void solve_kernel(
    const short* __restrict__ kn, const short* __restrict__ vn,
    const float* __restrict__ gdec, const float* __restrict__ beta,
    short* __restrict__ UvT, short* __restrict__ Tk) {
    __shared__ short Pn[64][72];
    __shared__ short Pt[64][72];
    __shared__ short UT[128][72];
    __shared__ float Ls[64];
    __shared__ float Bs[64];

    int wg   = blockIdx.x;
    int half = wg & 1;
    int c    = (wg >> 1) & 31;
    int bh   = wg >> 6;
    int b = bh >> 4, h = bh & 15;
    int tid = threadIdx.x;
    int wave = tid >> 6, lane = tid & 63;
    int quad = lane >> 4, l16 = lane & 15;

    const short* Kb = kn + ((size_t)(b * S_LEN + c * CT)) * KD + h * 128;
    const short* Vb = vn + ((size_t)(b * S_LEN + c * CT)) * KD + h * 128;

    if (wave == 0) {
        float lg = __logf(gdec[((size_t)(b * S_LEN + c * CT) + lane) * NH + h]);
#pragma unroll
        for (int off = 1; off < 64; off <<= 1) {
            float y = __shfl_up(lg, off);
            if (lane >= off) lg += y;
        }
        Ls[lane] = lg;
        Bs[lane] = beta[((size_t)(b * S_LEN + c * CT) + lane) * NH + h];
    }
    __syncthreads();

    // build P = -A
    {
        floatx4 acc[4];
#pragma unroll
        for (int i = 0; i < 4; ++i) acc[i] = (floatx4){0.f, 0.f, 0.f, 0.f};
        for (int ks = 0; ks < 4; ++ks) {
            short8 af = *(const short8*)(Kb + (size_t)(wave * 16 + l16) * KD + ks * 32 + quad * 8);
#pragma unroll
            for (int it = 0; it < 4; ++it) {
                short8 bf = *(const short8*)(Kb + (size_t)(it * 16 + l16) * KD + ks * 32 + quad * 8);
                acc[it] = MFMA(af, bf, acc[it]);
            }
        }
#pragma unroll
        for (int it = 0; it < 4; ++it) {
            int icol = it * 16 + l16;
#pragma unroll
            for (int r = 0; r < 4; ++r) {
                int trow = wave * 16 + quad * 4 + r;
                float v = 0.f;
                if (icol < trow) v = -Bs[trow] * __expf(Ls[trow] - Ls[icol]) * acc[it][r];
                short bv = f2bf(v);
                Pn[trow][icol] = bv;
                Pt[icol][trow] = bv;
            }
        }
    }

    // RHS -> UT (transposed [n][t])
    {
        const short* src = half ? Kb : Vb;
        int tr = tid >> 2, seg = (tid & 3) * 32;
        float s = Bs[tr] * (half ? __expf(Ls[tr]) : 1.f);
#pragma unroll
        for (int j = 0; j < 4; ++j) {
            short8 d = *(const short8*)(src + (size_t)tr * KD + seg + j * 8);
#pragma unroll
            for (int e = 0; e < 8; ++e)
                UT[seg + j * 8 + e][tr] = f2bf(bf2f(d[e]) * s);
        }
    }
    __syncthreads();

    // 6 applications U <- U + P U, squaring P between
    for (int iter = 0; iter < 6; ++iter) {
        floatx4 acc[8];
#pragma unroll
        for (int nt = 0; nt < 8; ++nt) {
            short4v u4 = *(const short4v*)&UT[nt * 16 + l16][wave * 16 + quad * 4];
            floatx4 a;
#pragma unroll
            for (int e = 0; e < 4; ++e) a[e] = bf2f(u4[e]);
            acc[nt] = a;
        }
        for (int ks = 0; ks < 2; ++ks) {
            short8 af = *(const short8*)&Pn[wave * 16 + l16][ks * 32 + quad * 8];
#pragma unroll
            for (int nt = 0; nt < 8; ++nt) {
                short8 bf = *(const short8*)&UT[nt * 16 + l16][ks * 32 + quad * 8];
                acc[nt] = MFMA(af, bf, acc[nt]);
            }
        }
        __syncthreads();
        if (iter < 5) {
#pragma unroll
            for (int nt = 0; nt < 8; ++nt) {
                short4v w4;
#pragma unroll
                for (int e = 0; e < 4; ++e) w4[e] = f2bf(acc[nt][e]);
                *(short4v*)&UT[nt * 16 + l16][wave * 16 + quad * 4] = w4;
            }
            floatx4 pacc[4];
#pragma unroll
            for (int it = 0; it < 4; ++it) pacc[it] = (floatx4){0.f, 0.f, 0.f, 0.f};
            for (int ks = 0; ks < 2; ++ks) {
                short8 paf = *(const short8*)&Pn[wave * 16 + l16][ks * 32 + quad * 8];
#pragma unroll
                for (int it = 0; it < 4; ++it) {
                    short8 pbf = *(const short8*)&Pt[it * 16 + l16][ks * 32 + quad * 8];
                    pacc[it] = MFMA(paf, pbf, pacc[it]);
                }
            }
            __syncthreads();
#pragma unroll
            for (int it = 0; it < 4; ++it) {
                int icol = it * 16 + l16;
#pragma unroll
                for (int r = 0; r < 4; ++r) {
                    int trow = wave * 16 + quad * 4 + r;
                    short bv = f2bf(pacc[it][r]);
                    Pn[trow][icol] = bv;
                    Pt[icol][trow] = bv;
                }
            }
            __syncthreads();
        } else {
            size_t cb = (size_t)(bh * NC + c);
            if (half == 0) {
#pragma unroll
                for (int nt = 0; nt < 8; ++nt) {
                    short4v w4;
#pragma unroll
                    for (int e = 0; e < 4; ++e) w4[e] = f2bf(acc[nt][e]);
                    *(short4v*)(UvT + (cb * 128 + nt * 16 + l16) * 64 + wave * 16 + quad * 4) = w4;
                }
            } else {
#pragma unroll
                for (int nt = 0; nt < 8; ++nt)
#pragma unroll
                    for (int r = 0; r < 4; ++r)
                        Tk[(cb * 64 + wave * 16 + quad * 4 + r) * 128 + nt * 16 + l16] = f2bf(acc[nt][r]);
            }
        }
    }
}

// ---------------- chunk prep B: W, Qg, KtilT, gam63 ----------------
__global__ __launch_bounds__(256) void prepb_kernel(
    const short* __restrict__ qn, const short* __restrict__ kn,
    const float* __restrict__ gdec,
    short* __restrict__ Wb_, short* __restrict__ Qg,
    short* __restrict__ KtT, float* __restrict__ gam63) {
    __shared__ short KT[128][72];
    __shared__ float Ls[64];
    int wg = blockIdx.x;
    int c = wg & 31, bh = wg >> 5;
    int b = bh >> 4, h = bh & 15;
    int tid = threadIdx.x, wave = tid >> 6, lane = tid & 63;
    int quad = lane >> 4, l16 = lane & 15;
    const short* Qb = qn + ((size_t)(b * S_LEN + c * CT)) * KD + h * 128;
    const short* Kb = kn + ((size_t)(b * S_LEN + c * CT)) * KD + h * 128;

    if (wave == 0) {
        float lg = __logf(gdec[((size_t)(b * S_LEN + c * CT) + lane) * NH + h]);
#pragma unroll
        for (int off = 1; off < 64; off <<= 1) {
            float y = __shfl_up(lg, off);
            if (lane >= off) lg += y;
        }
        Ls[lane] = lg;
    }
    __syncthreads();
    size_t cb = (size_t)(bh * NC + c);
    if (tid == 0) gam63[cb] = __expf(Ls[63]);

    // W = mask_{i<=t} e^{L_t-L_i} (q_t.k_i)
    {
        floatx4 acc[4];
#pragma unroll
        for (int i = 0; i < 4; ++i) acc[i] = (floatx4){0.f, 0.f, 0.f, 0.f};
        for (int ks = 0; ks < 4; ++ks) {
            short8 af = *(const short8*)(Qb + (size_t)(wave * 16 + l16) * KD + ks * 32 + quad * 8);
#pragma unroll
            for (int it = 0; it < 4; ++it) {
                short8 bf = *(const short8*)(Kb + (size_t)(it * 16 + l16) * KD + ks * 32 + quad * 8);
                acc[it] = MFMA(af, bf, acc[it]);
            }
        }
#pragma unroll
        for (int it = 0; it < 4; ++it) {
            int icol = it * 16 + l16;
#pragma unroll
            for (int r = 0; r < 4; ++r) {
                int trow = wave * 16 + quad * 4 + r;
                float v = (icol <= trow) ? __expf(Ls[trow] - Ls[icol]) * acc[it][r] : 0.f;
                Wb_[(cb * 64 + trow) * 64 + icol] = f2bf(v);
            }
        }
    }

    // Qg rows (e^{L_t} q_t)  +  stage scaled-K transpose
    {
        int tr = tid >> 2, seg = (tid & 3) * 32;
        float sq = __expf(Ls[tr]);
        float sk = __expf(Ls[63] - Ls[tr]);
#pragma unroll
        for (int j = 0; j < 4; ++j) {
            short8 dq = *(const short8*)(Qb + (size_t)tr * KD + seg + j * 8);
            short8 dk = *(const short8*)(Kb + (size_t)tr * KD + seg + j * 8);
            short8 oq;
#pragma unroll
            for (int e = 0; e < 8; ++e) {
                oq[e] = f2bf(bf2f(dq[e]) * sq);
                KT[seg + j * 8 + e][tr] = f2bf(bf2f(dk[e]) * sk);
            }
            *(short8*)(Qg + (cb * 64 + tr) * 128 + seg + j * 8) = oq;
        }
    }
    __syncthreads();
    {
        int dk = tid >> 1, seg = (tid & 1) * 32;
#pragma unroll
        for (int j = 0; j < 4; ++j) {
            short8 v = *(const short8*)&KT[dk][seg + j * 8];
            *(short8*)(KtT + (cb * 128 + dk) * 64 + seg + j * 8) = v;
        }
    }
}

// ---------------- sequential chunk pass: register-double-buffered prefetch ----------------
// WG = (bh, vhalf). fp32 state in regs (sacc) + bf16 copy in LDS (ST, v-major).
// All chunk operands prefetched one chunk ahead into registers (~224 VGPR dbuf).
__global__ __launch_bounds__(256, 1) void seq_kernel(
    const short* __restrict__ UvT, const short* __restrict__ Tk,
    const short* __restrict__ Wb_, const short* __restrict__ Qg,
    const short* __restrict__ KtT, const float* __restrict__ gam63,
    short* __restrict__ ob) {
    __shared__ short ST[64][136];
    __shared__ short UTs[64][72];
    int wg = blockIdx.x;
    int vh = wg & 1, bh = wg >> 1;
    int b = bh >> 4, h = bh & 15;
    int tid = threadIdx.x, wave = tid >> 6, lane = tid & 63;
    int quad = lane >> 4, l16 = lane & 15;

    for (int i = tid; i < 64 * 136; i += 256) ((short*)ST)[i] = 0;
    floatx4 sacc[8];
#pragma unroll
    for (int i = 0; i < 8; ++i) sacc[i] = (floatx4){0.f, 0.f, 0.f, 0.f};
    __syncthreads();

    short8 tkA[4], qgA[4], wA[2], ktA[16]; short4v uvA[4]; float gamA;
    short8 tkB[4], qgB[4], wB[2], ktB[16]; short4v uvB[4]; float gamB;

#define LOADF(tkX, qgX, wX, ktX, uvX, gamX, c)                                              \
    {                                                                                       \
        size_t cb = (size_t)(bh * NC + (c));                                                \
        const short* Tkc = Tk  + cb * 64 * 128;                                             \
        const short* Qgc = Qg  + cb * 64 * 128;                                             \
        const short* Wc  = Wb_ + cb * 64 * 64;                                              \
        const short* Ktc = KtT + cb * 128 * 64;                                             \
        const short* Uvc = UvT + (cb * 128 + (size_t)vh * 64) * 64;                         \
        _Pragma("unroll")                                                                   \
        for (int ks = 0; ks < 4; ++ks) {                                                    \
            tkX[ks] = *(const short8*)(Tkc + (size_t)(wave * 16 + l16) * 128 + ks * 32 + quad * 8); \
            qgX[ks] = *(const short8*)(Qgc + (size_t)(wave * 16 + l16) * 128 + ks * 32 + quad * 8); \
        }                                                                                   \
        _Pragma("unroll")                                                                   \
        for (int ks = 0; ks < 2; ++ks)                                                      \
            wX[ks] = *(const short8*)(Wc + (size_t)(wave * 16 + l16) * 64 + ks * 32 + quad * 8); \
        _Pragma("unroll")                                                                   \
        for (int dt = 0; dt < 8; ++dt)                                                      \
            _Pragma("unroll")                                                               \
            for (int ks = 0; ks < 2; ++ks)                                                  \
                ktX[dt * 2 + ks] = *(const short8*)(Ktc + (size_t)(dt * 16 + l16) * 64 + ks * 32 + quad * 8); \
        _Pragma("unroll")                                                                   \
        for (int vt = 0; vt < 4; ++vt)                                                      \
            uvX[vt] = *(const short4v*)(Uvc + (size_t)(vt * 16 + l16) * 64 + wave * 16 + quad * 4); \
        gamX = gam63[cb];                                                                   \
    }

#define BODY(tkX, qgX, wX, ktX, uvX, gamX, c)                                               \
    {                                                                                       \
        floatx4 uacc[4], oacc[4];                                                           \
        _Pragma("unroll")                                                                   \
        for (int vt = 0; vt < 4; ++vt) {                                                    \
            floatx4 a;                                                                      \
            _Pragma("unroll")                                                               \
            for (int e = 0; e < 4; ++e) a[e] = bf2f(uvX[vt][e]);                            \
            uacc[vt] = a;                                                                   \
            oacc[vt] = (floatx4){0.f, 0.f, 0.f, 0.f};                                       \
        }                                                                                   \
        _Pragma("unroll")                                                                   \
        for (int ks = 0; ks < 4; ++ks) {                                                    \
            short8 afT = neg8(tkX[ks]);                                                     \
            _Pragma("unroll")                                                               \
            for (int vt = 0; vt < 4; ++vt) {                                                \
                short8 bf = *(const short8*)&ST[vt * 16 + l16][ks * 32 + quad * 8];         \
                uacc[vt] = MFMA(afT, bf, uacc[vt]);                                         \
                oacc[vt] = MFMA(qgX[ks], bf, oacc[vt]);                                     \
            }                                                                               \
        }                                                                                   \
        _Pragma("unroll")                                                                   \
        for (int vt = 0; vt < 4; ++vt) {                                                    \
            short4v w4;                                                                     \
            _Pragma("unroll")                                                               \
            for (int e = 0; e < 4; ++e) w4[e] = f2bf(uacc[vt][e]);                          \
            *(short4v*)&UTs[vt * 16 + l16][wave * 16 + quad * 4] = w4;                      \
        }                                                                                   \
        __syncthreads();                                                                    \
        _Pragma("unroll")                                                                   \
        for (int ks = 0; ks < 2; ++ks) {                                                    \
            _Pragma("unroll")                                                               \
            for (int vt = 0; vt < 4; ++vt) {                                                \
                short8 bf = *(const short8*)&UTs[vt * 16 + l16][ks * 32 + quad * 8];        \
                oacc[vt] = MFMA(wX[ks], bf, oacc[vt]);                                      \
            }                                                                               \
        }                                                                                   \
        _Pragma("unroll")                                                                   \
        for (int vt = 0; vt < 4; ++vt)                                                      \
            _Pragma("unroll")                                                               \
            for (int r = 0; r < 4; ++r) {                                                   \
                int m = b * S_LEN + (c) * CT + wave * 16 + quad * 4 + r;                    \
                ob[(size_t)m * VD + h * 128 + vh * 64 + vt * 16 + l16] = f2bf(oacc[vt][r]); \
            }                                                                               \
        _Pragma("unroll")                                                                   \
        for (int dt = 0; dt < 8; ++dt)                                                      \
            _Pragma("unroll")                                                               \
            for (int e = 0; e < 4; ++e) sacc[dt][e] *= gamX;                                \
        _Pragma("unroll")                                                                   \
        for (int ks = 0; ks < 2; ++ks) {                                                    \
            short8 af = *(const short8*)&UTs[wave * 16 + l16][ks * 32 + quad * 8];          \
            _Pragma("unroll")                                                               \
            for (int dt = 0; dt < 8; ++dt)                                                  \
                sacc[dt] = MFMA(af, ktX[dt * 2 + ks], sacc[dt]);                            \
        }                                                                                   \
        _Pragma("unroll")                                                                   \
        for (int dt = 0; dt < 8; ++dt)                                                      \
            _Pragma("unroll")                                                               \
            for (int r = 0; r < 4; ++r)                                                     \
                ST[wave * 16 + quad * 4 + r][dt * 16 + l16] = f2bf(sacc[dt][r]);            \
        __syncthreads();                                                                    \
    }

    LOADF(tkA, qgA, wA, ktA, uvA, gamA, 0)
    for (int c = 0; c < NC; c += 2) {
        LOADF(tkB, qgB, wB, ktB, uvB, gamB, c + 1)
        BODY(tkA, qgA, wA, ktA, uvA, gamA, c)
        if (c + 2 < NC) LOADF(tkA, qgA, wA, ktA, uvA, gamA, c + 2)
        BODY(tkB, qgB, wB, ktB, uvB, gamB, c + 1)
    }
#undef LOADF
#undef BODY
}

// ---------------- RMSNorm + SiLU gate (bf16 in/out) ----------------
__global__ __launch_bounds__(256) void rms_gate_kernel(
    const short* __restrict__ o, const short* __restrict__ graw,
    const float* __restrict__ nw, short* __restrict__ og) {
    __shared__ float red[4];
    int m = blockIdx.x, t = threadIdx.x;
    short8 a = ((const short8*)(o + (size_t)m * VD))[t];
    float av[8];
#pragma unroll
    for (int i = 0; i < 8; ++i) av[i] = bf2f(a[i]);
    float ss = 0.f;
#pragma unroll
    for (int i = 0; i < 8; ++i) ss += av[i] * av[i];
#pragma unroll
    for (int off = 1; off < 64; off <<= 1) ss += __shfl_xor(ss, off);
    if ((t & 63) == 0) red[t >> 6] = ss;
    __syncthreads();
    float tot = red[0] + red[1] + red[2] + red[3];
    float sc = rsqrtf(tot * (1.f / VD) + 1e-6f);
    short8 gv = ((const short8*)(graw + (size_t)m * VD))[t];
    float4 n0 = ((const float4*)nw)[2 * t];
    float4 n1 = ((const float4*)nw)[2 * t + 1];
    const float* na = (const float*)&n0;
    const float* nb = (const float*)&n1;
    short8 ov;
#pragma unroll
    for (int i = 0; i < 4; ++i) ov[i]     = f2bf(av[i]     * sc * na[i] * silu_f(bf2f(gv[i])));
#pragma unroll
    for (int i = 0; i < 4; ++i) ov[i + 4] = f2bf(av[i + 4] * sc * nb[i] * silu_f(bf2f(gv[i + 4])));
    ((short8*)(og + (size_t)m * VD))[t] = ov;
}

// ---------------- host launcher ----------------
extern "C" void kernel_launch(void* const* d_in, const int* in_sizes, int n_in,
                              void* d_out, int out_size, void* d_ws, size_t ws_size,
                              hipStream_t stream) {
    const float* x    = (const float*)d_in[0];
    const float* Wq   = (const float*)d_in[1];
    const float* Wk   = (const float*)d_in[2];
    const float* Wv   = (const float*)d_in[3];
    const float* Wa   = (const float*)d_in[4];
    const float* Wb   = (const float*)d_in[5];
    const float* Wg   = (const float*)d_in[6];
    const float* Wo   = (const float*)d_in[7];
    const float* cwq  = (const float*)d_in[8];
    const float* cbq  = (const float*)d_in[9];
    const float* cwk  = (const float*)d_in[10];
    const float* cbk  = (const float*)d_in[11];
    const float* cwv  = (const float*)d_in[12];
    const float* cbv  = (const float*)d_in[13];
    const float* Alog = (const float*)d_in[14];
    const float* dtb  = (const float*)d_in[15];
    const float* nw   = (const float*)d_in[16];

    char* ws = (char*)d_ws;
    short* Wob = (short*)(ws);
    short* xb  = (short*)(ws + 8 * MB);
    short* Wqb = (short*)(ws + 24 * MB);
    short* Wkb = (short*)(ws + 32 * MB);
    short* Wvb = (short*)(ws + 40 * MB);
    short* Wgb = (short*)(ws + 48 * MB);
    short* qrb = (short*)(ws + 56 * MB);
    short* krb = (short*)(ws + 72 * MB);
    short* vrb = (short*)(ws + 88 * MB);
    short* grb = (short*)(ws + 104 * MB);
    short* qnb = (short*)(ws + 8 * MB);
    short* knb = (short*)(ws + 24 * MB);
    short* vnb = (short*)(ws + 40 * MB);
    float* gdec = (float*)(ws + 120 * MB);
    float* beta = (float*)(ws + 120 * MB + 262144);
    short* ob  = qrb;   // reuse
    short* ogb = krb;   // reuse
    // chunked-scan buffers
    short* UvT  = (short*)(ws + 121 * MB);   // [1024][128][64]
    short* Tkb  = (short*)(ws + 137 * MB);   // [1024][64][128]
    short* Wbuf = (short*)(ws + 153 * MB);   // [1024][64][64]
    short* Qgb  = (short*)(ws + 161 * MB);   // [1024][64][128]
    short* KtT  = (short*)(ws + 177 * MB);   // [1024][128][64]
    float* gm63 = (float*)(ws + 193 * MB);   // [1024]

    // 1. fp32 -> bf16 conversions (single launch)
    cvt_all_kernel<<<dim3(4096, 6), 256, 0, stream>>>(x, Wq, Wk, Wv, Wg, Wo,
                                                      xb, Wqb, Wkb, Wvb, Wgb, Wob);

    // 2. a/b projection + decay/beta
    ab_kernel<<<4096, 256, 0, stream>>>(x, Wa, Wb, Alog, dtb, gdec, beta);

    // 3. fused q/k/v/gate projections
    gemm_qkvg<<<dim3(32, 16, 4), 256, 0, stream>>>(xb, Wqb, Wkb, Wvb, Wgb,
                                                   qrb, krb, vrb, grb);

    // 4. causal conv + SiLU + l2norm
    conv_kernel<<<16384, 256, 0, stream>>>(qrb, krb, vrb,
                                           cwq, cbq, cwk, cbk, cwv, cbv, qnb, knb, vnb);

    // 5. chunked delta-rule
    solve_kernel<<<2048, 256, 0, stream>>>(knb, vnb, gdec, beta, UvT, Tkb);
    prepb_kernel<<<1024, 256, 0, stream>>>(qnb, knb, gdec, Wbuf, Qgb, KtT, gm63);
    seq_kernel<<<64, 256, 0, stream>>>(UvT, Tkb, Wbuf, Qgb, KtT, gm63, ob);

    // 6. RMSNorm + SiLU gate
    rms_gate_kernel<<<4096, 256, 0, stream>>>(ob, grb, nw, ogb);

    // 7. output projection
    gemm_out<<<dim3(32, 16, 1), 256, 0, stream>>>(ogb, Wob, (float*)d_out);
}